// Round 9
// baseline (188.558 us; speedup 1.0000x reference)
//
#include <hip/hip_runtime.h>
#include <hip/hip_bf16.h>

typedef unsigned short u16;
typedef unsigned int u32;
typedef unsigned char u8;
typedef __attribute__((ext_vector_type(8))) short bf16x8;
typedef __attribute__((ext_vector_type(4))) float f32x4;

#define DEV __device__ __forceinline__

DEV float bf2f(u16 u) { union { u32 i; float f; } c; c.i = ((u32)u) << 16; return c.f; }
DEV u16 f2bf(float f) {  // round-to-nearest-even
  union { float f; u32 i; } c; c.f = f;
  u32 r = c.i + 0x7FFFu + ((c.i >> 16) & 1u);
  return (u16)(r >> 16);
}
DEV u32 pk2(float lo, float hi) { return (u32)f2bf(lo) | ((u32)f2bf(hi) << 16); }
DEV float rdsrc(const void* p, int e, int isb) {
  return isb ? bf2f(((const u16*)p)[e]) : ((const float*)p)[e];
}
DEV bf16x8 as_bf(uint4 v) { union { uint4 u; bf16x8 h; } c; c.u = v; return c.h; }

static constexpr int B = 2, N = 512, D = 128, F = 512;
static constexpr int NROW = B * N;  // 1024
static constexpr float EPS = 1e-5f;
static constexpr float NEG = -1e9f;
static constexpr float SCALE = 0.08838834764831845f;  // 1/sqrt(128)

// ---- fp32 small-weight region offsets ------------------------------------
#define OFF_PRE_W   0
#define OFF_PRE_B   256
#define OFF_PROJ_B  33152
#define OFF_BN_G    49664
#define OFF_BN_B    49792
#define OFF_BN_M    49920
#define OFF_BN_V    50048
#define OFF_OUT_B2  66560
#define OFF_PE      66688
#define OFF_BQ      132224
#define OFF_BK      181760
#define OFF_BV      231296
#define OFF_BO      280832
#define OFF_LN1G    281216
#define OFF_LN1B    281600
#define OFF_LN2G    281984
#define OFF_LN2B    282368
#define OFF_FB1     479360
#define OFF_FB2     677504
#define W_TOTAL     677888

// ---- packed-bf16 weight region (u32 units; [e8][col] uint4 of 8 K-elems) --
static constexpr int PB_PROJ = 0;
static constexpr int PB_OW1  = 8192;
static constexpr int PB_OW2  = 16384;
static constexpr int PB_L0   = 24576;
static constexpr int PB_LSTR = 98304;
static constexpr int PB_WO   = 24576;
static constexpr int PB_FW1  = 32768;
static constexpr int PB_FW2  = 65536;
static constexpr int PTOT    = 79872;   // total uint4 pack entries

struct NEnt { const void* s; int off, n; };
struct PEnt { const void* s1; const void* s2; int o1, o2, dst, lgn, cum; };
struct PrepArgs { NEnt nrm[19]; PEnt pk[21]; };

// ---------------------------------------------------------------------------
// Grid barrier: counters zeroed by in-graph hipMemsetAsync each call.
// All 256 blocks are co-resident (256 blocks, >=2 blocks/CU capacity).
// ---------------------------------------------------------------------------
DEV void gsync(int* c, int nblk) {
  __syncthreads();
  if (threadIdx.x == 0) {
    __threadfence();   // publish this block's writes (flushes its XCD L2 path)
    __hip_atomic_fetch_add(c, 1, __ATOMIC_ACQ_REL, __HIP_MEMORY_SCOPE_AGENT);
    while (__hip_atomic_load(c, __ATOMIC_ACQUIRE, __HIP_MEMORY_SCOPE_AGENT) < nblk)
      __builtin_amdgcn_s_sleep(8);
    __threadfence();
  }
  __syncthreads();
}

// ---------------------------------------------------------------------------
// MFMA helpers (round-8 verified): A = 4 real rows (rows 4..15 zero) packed
// [e8][16] uint4 in LDS; B = [e8][ncol] uint4. D rows 0..3 -> lanes 0..15,
// regs 0..3 (gfx950 C/D map: col=lane&15, row=(lane>>4)*4+reg).
// ---------------------------------------------------------------------------
template<int KT>
DEV f32x4 mmaK(const uint4* __restrict__ aPk, const uint4* __restrict__ Bp,
               int ncol, int col, int lane) {
  f32x4 acc = {0.f, 0.f, 0.f, 0.f};
  const int sub = lane >> 4;
  #pragma unroll
  for (int kt = 0; kt < KT; ++kt) {
    const int e8 = kt * 4 + sub;
    acc = __builtin_amdgcn_mfma_f32_16x16x32_bf16(
        as_bf(aPk[e8 * 16 + (lane & 15)]),
        as_bf(Bp[(size_t)e8 * ncol + col]),
        acc, 0, 0, 0);
  }
  return acc;
}

DEV void packA(const float* __restrict__ src, int ld, int K,
               uint4* __restrict__ aPk, int t) {
  const int n = (K >> 3) * 4;
  for (int i = t; i < n; i += 512) {
    const int e8 = i >> 2, r = i & 3;
    const float* s = src + r * ld + e8 * 8;
    uint4 w;
    w.x = pk2(s[0], s[1]); w.y = pk2(s[2], s[3]);
    w.z = pk2(s[4], s[5]); w.w = pk2(s[6], s[7]);
    aPk[e8 * 16 + r] = w;
  }
}

// ---------------------------------------------------------------------------
// k_all: fused prep + relchain/QKV0 + 3 transformer layers; grid barriers
// between stages. 256 blocks x 512 threads.
// ---------------------------------------------------------------------------
__global__ __launch_bounds__(512) void k_all(PrepArgs pa,
    const void* __restrict__ relv, const void* __restrict__ bnv,
    const void* __restrict__ maskp, const int* __restrict__ agent_id,
    int* __restrict__ bar, int* __restrict__ mbuf,
    float* __restrict__ xbuf, float* __restrict__ q0, float* __restrict__ q1,
    u32* __restrict__ kT0, u32* __restrict__ kT1,
    u32* __restrict__ vT0, u32* __restrict__ vT1,
    float* __restrict__ W, u32* __restrict__ Wb, float* __restrict__ outp)
{
  const int t = threadIdx.x;            // 0..511
  const int blk = blockIdx.x;           // 0..255
  const int row0 = blk * 4;
  const int b = row0 >> 9;
  const int wid = t >> 6;
  const int lane = t & 63;

  // Phase-overlapped shared memory (~37 KB)
  __shared__ float bufA[4][512];                 // p / hs / pB(relq)
  __shared__ float r0[4][128], r1[4][128], r2[4][128], r3[4][128], r4[4][128];
  __shared__ uint4 aPk[1024];
  __shared__ float wred[8][9];
  __shared__ float sT0[4], sT1[4];
  __shared__ float sMt, den[4];
  __shared__ int s_nb, s_m4, s_m2;

  // =========================== stage 0: prep ==============================
  if (t == 0) { s_nb = 0; s_m4 = 0; s_m2 = 0; }
  __syncthreads();
  if (t < 64) {
    const u32 w = ((const u32*)bnv)[t];
    if (((w >> 8) & 0xFFu) != 0x3Fu || ((w >> 24) & 0xFFu) != 0x3Fu)
      atomicOr(&s_nb, 1);
  }
  __syncthreads();
  const int isb = s_nb ? 0 : 1;

  // norm small tensors to fp32 W
  for (int ten = 0; ten < 19; ++ten) {
    const NEnt E = pa.nrm[ten];
    for (int e = blk * 512 + t; e < E.n; e += 256 * 512)
      W[E.off + e] = rdsrc(E.s, e, isb);
  }
  // pack big weights (bf16, [e8][col] uint4)
  for (int g = blk * 512 + t; g < PTOT; g += 256 * 512) {
    int ei = 0;
    #pragma unroll
    for (int k = 1; k < 21; ++k) if (g >= pa.pk[k].cum) ei = k;
    const PEnt E = pa.pk[ei];
    const int li = g - E.cum;
    const int e8 = li >> E.lgn, c = li & ((1 << E.lgn) - 1);
    float f[8];
    #pragma unroll
    for (int i = 0; i < 8; ++i) {
      const int si = ((e8 * 8 + i) << E.lgn) + c;
      f[i] = rdsrc(E.s1, E.o1 + si, isb);
      if (E.s2) f[i] += rdsrc(E.s2, E.o2 + si, isb);
    }
    uint4 w;
    w.x = pk2(f[0], f[1]); w.y = pk2(f[2], f[3]);
    w.z = pk2(f[4], f[5]); w.w = pk2(f[6], f[7]);
    ((uint4*)(Wb + E.dst))[li] = w;
  }
  // mask normalization (block 255)
  if (blk == 255) {
    if (t < 256) {
      const u32 w = ((const u32*)maskp)[t];
      if (!(w == 0u || w == 1u || w == 0x3F800000u)) atomicOr(&s_m4, 1);
      if (!(w == 0u || w == 1u || w == 0x10000u || w == 0x10001u ||
            w == 0x3F80u || w == 0x3F800000u || w == 0x3F803F80u)) atomicOr(&s_m2, 1);
    }
    __syncthreads();
    const int mode = (!s_m4) ? 4 : ((!s_m2) ? 2 : 1);
    #pragma unroll
    for (int k = 0; k < 2; ++k) {
      const int e = k * 512 + t;
      int v;
      if (mode == 4)      v = (((const u32*)maskp)[e] != 0u);
      else if (mode == 2) v = (((const u16*)maskp)[e] != 0);
      else                v = (((const u8*)maskp)[e]  != 0);
      mbuf[e] = v;
    }
  }
  gsync(bar + 0, 256);

  // ====================== stage 1: relchain + QKV(0) ======================
  // r0=pl r1=zl r2=rl r3=os r4=pA bufA(first128)=pB
  {
    float s0[4] = {0, 0, 0, 0}, s1[4] = {0, 0, 0, 0}, cnt;
    {
      const int j = t;
      const float m = (float)mbuf[b * N + j];
      cnt = m;
      if (isb) {
        const u32* rel2 = (const u32*)relv;
        #pragma unroll
        for (int r = 0; r < 4; ++r) {
          const u32 u = rel2[(size_t)(row0 + r) * N + j];
          s0[r] += m * bf2f((u16)(u & 0xFFFFu));
          s1[r] += m * bf2f((u16)(u >> 16));
        }
      } else {
        const float2* relf = (const float2*)relv;
        #pragma unroll
        for (int r = 0; r < 4; ++r) {
          const float2 u = relf[(size_t)(row0 + r) * N + j];
          s0[r] += m * u.x; s1[r] += m * u.y;
        }
      }
    }
    {
      const uint4 z = {0u, 0u, 0u, 0u};
      aPk[t] = z; aPk[t + 512] = z;
    }
    #pragma unroll
    for (int o = 32; o > 0; o >>= 1) {
      #pragma unroll
      for (int r = 0; r < 4; ++r) {
        s0[r] += __shfl_xor(s0[r], o, 64);
        s1[r] += __shfl_xor(s1[r], o, 64);
      }
      cnt += __shfl_xor(cnt, o, 64);
    }
    if ((t & 63) == 0) {
      #pragma unroll
      for (int r = 0; r < 4; ++r) { wred[wid][r] = s0[r]; wred[wid][4 + r] = s1[r]; }
      wred[wid][8] = cnt;
    }
    __syncthreads();
    if (t < 4) {
      float a0 = 0, a1 = 0;
      #pragma unroll
      for (int w = 0; w < 8; ++w) { a0 += wred[w][t]; a1 += wred[w][4 + t]; }
      sT0[t] = a0; sT1[t] = a1;
    }
    if (t == 8) {
      float c = 0;
      #pragma unroll
      for (int w = 0; w < 8; ++w) c += wred[w][8];
      sMt = c;
    }
    __syncthreads();

    // P2: pooled
    {
      const int r = t >> 7, c = t & 127;
      const int mi = mbuf[row0 + r];
      r0[r][c] = mi ? (sT0[r] * W[OFF_PRE_W + c] + sT1[r] * W[OFF_PRE_W + D + c]) / sMt
                      + W[OFF_PRE_B + c]
                    : 0.f;
    }
    __syncthreads();

    // P3: pooled @ (P1+P2)
    packA(&r0[0][0], D, D, aPk, t);
    __syncthreads();
    {
      const int col = wid * 16 + (lane & 15);
      f32x4 acc = mmaK<4>(aPk, (const uint4*)(Wb + PB_PROJ), 128, col, lane);
      if (lane < 16) {
        #pragma unroll
        for (int g = 0; g < 4; ++g) r4[g][col] = acc[g];
      }
    }
    __syncthreads();
    {
      const int r = t >> 7, d = t & 127;
      r1[r][d] = mbuf[row0 + r] ? r4[r][d] + W[OFF_PROJ_B + d] : 0.f;
    }
    __syncthreads();

    // P4: z @ out_w1; bn; relu
    packA(&r1[0][0], D, D, aPk, t);
    __syncthreads();
    {
      const int col = wid * 16 + (lane & 15);
      f32x4 acc = mmaK<4>(aPk, (const uint4*)(Wb + PB_OW1), 128, col, lane);
      if (lane < 16) {
        #pragma unroll
        for (int g = 0; g < 4; ++g) r4[g][col] = acc[g];
      }
    }
    __syncthreads();
    {
      const int r = t >> 7, d = t & 127;
      const float hb = (r4[r][d] - W[OFF_BN_M + d]) * __frsqrt_rn(W[OFF_BN_V + d] + EPS)
                       * W[OFF_BN_G + d] + W[OFF_BN_B + d];
      r2[r][d] = fmaxf(hb, 0.f);
    }
    __syncthreads();

    // P5: relu_h @ out_w2 + out_b2 + pe
    packA(&r2[0][0], D, D, aPk, t);
    __syncthreads();
    {
      const int col = wid * 16 + (lane & 15);
      f32x4 acc = mmaK<4>(aPk, (const uint4*)(Wb + PB_OW2), 128, col, lane);
      if (lane < 16) {
        #pragma unroll
        for (int g = 0; g < 4; ++g) r4[g][col] = acc[g];
      }
    }
    __syncthreads();
    {
      const int r = t >> 7, d = t & 127;
      const int aid = agent_id[row0 + r];
      const float x0 = r4[r][d] + W[OFF_OUT_B2 + d] + W[OFF_PE + aid * D + d];
      r3[r][d] = x0;
      xbuf[(size_t)(row0 + r) * D + d] = x0;
    }
    __syncthreads();

    // P6: QKV layer 0 (K -> r4, V -> bufA[.][0..127])
    packA(&r3[0][0], D, D, aPk, t);
    __syncthreads();
    {
      const int col = wid * 16 + (lane & 15);
      #pragma unroll
      for (int m = 0; m < 3; ++m) {
        f32x4 acc = mmaK<4>(aPk, (const uint4*)(Wb + PB_L0 + m * 8192), 128, col, lane);
        if (lane < 16) {
          const float bb = W[(m == 0 ? OFF_BQ : m == 1 ? OFF_BK : OFF_BV) + col];
          if (m == 0) {
            #pragma unroll
            for (int g = 0; g < 4; ++g) q0[(size_t)(row0 + g) * D + col] = acc[g] + bb;
          } else if (m == 1) {
            #pragma unroll
            for (int g = 0; g < 4; ++g) r4[g][col] = acc[g] + bb;
          } else {
            #pragma unroll
            for (int g = 0; g < 4; ++g) bufA[g][col] = acc[g] + bb;
          }
        }
      }
    }
    __syncthreads();
    if (t < 64) {   // packed K^T: [b][e8][j] uint4
      const int r = t >> 4, e8 = t & 15;
      const float* ks = r4[r];
      uint4 w;
      w.x = pk2(ks[8 * e8 + 0], ks[8 * e8 + 1]);
      w.y = pk2(ks[8 * e8 + 2], ks[8 * e8 + 3]);
      w.z = pk2(ks[8 * e8 + 4], ks[8 * e8 + 5]);
      w.w = pk2(ks[8 * e8 + 6], ks[8 * e8 + 7]);
      ((uint4*)kT0)[((size_t)b * 16 + e8) * 512 + (row0 & 511) + r] = w;
    }
    if (t < 128) {  // packed V: [b][j8][d] uint4 (half per block)
      const int i0 = row0 & 511, j8 = i0 >> 3, h = (i0 >> 2) & 1;
      uint2 w;
      w.x = pk2(bufA[0][t], bufA[1][t]);
      w.y = pk2(bufA[2][t], bufA[3][t]);
      *(uint2*)(vT0 + (((size_t)b * 64 + j8) * 128 + t) * 4 + 2 * h) = w;
    }
  }
  gsync(bar + 1, 256);

  // ========================= stages 2-4: layers ===========================
  // r0=qs bufA=p/hs r1=os r2=xs r3=pA r4=pB
  for (int l = 0; l < 3; ++l) {
    const int last = (l == 2);
    const float* qin = (l & 1) ? q1 : q0;
    float*       qout = (l & 1) ? q0 : q1;
    const u32*   kin = (l & 1) ? kT1 : kT0;
    u32*         kout = (l & 1) ? kT0 : kT1;
    const u32*   vin = (l & 1) ? vT1 : vT0;
    u32*         vout = (l & 1) ? vT0 : vT1;

    const uint4* WOp = (const uint4*)(Wb + PB_L0 + l * PB_LSTR + PB_WO);
    const uint4* W1p = (const uint4*)(Wb + PB_L0 + l * PB_LSTR + PB_FW1);
    const uint4* W2p = (const uint4*)(Wb + PB_L0 + l * PB_LSTR + PB_FW2);
    const float* bo  = W + OFF_BO  + l * D;
    const float* g1  = W + OFF_LN1G + l * D;
    const float* b1  = W + OFF_LN1B + l * D;
    const float* fb1 = W + OFF_FB1 + l * F;
    const float* fb2 = W + OFF_FB2 + l * D;
    const float* g2  = W + OFF_LN2G + l * D;
    const float* b2v = W + OFF_LN2B + l * D;

    // A: load Q rows pre-scaled
    {
      const int r = t >> 7, d = t & 127;
      r0[r][d] = qin[(size_t)(row0 + r) * D + d] * SCALE;
    }
    __syncthreads();

    // B: scores via MFMA
    packA(&r0[0][0], D, D, aPk, t);
    __syncthreads();
    {
      const uint4* Kp = (const uint4*)kin + (size_t)b * 16 * 512;
      #pragma unroll
      for (int i = 0; i < 4; ++i) {
        const int col = (wid * 4 + i) * 16 + (lane & 15);
        f32x4 acc = mmaK<4>(aPk, Kp, 512, col, lane);
        if (lane < 16) {
          const float bias = mbuf[b * N + col] ? 0.f : NEG;
          #pragma unroll
          for (int g = 0; g < 4; ++g) bufA[g][col] = acc[g] + bias;
        }
      }
    }
    __syncthreads();

    // C: softmax — wave w handles row w
    if (wid < 4) {
      const int r = wid;
      float pv[8];
      float mx = -1e30f;
      #pragma unroll
      for (int k = 0; k < 8; ++k) { pv[k] = bufA[r][lane + 64 * k]; mx = fmaxf(mx, pv[k]); }
      #pragma unroll
      for (int o = 32; o > 0; o >>= 1) mx = fmaxf(mx, __shfl_xor(mx, o, 64));
      float sum = 0.f;
      #pragma unroll
      for (int k = 0; k < 8; ++k) { pv[k] = __expf(pv[k] - mx); sum += pv[k]; }
      #pragma unroll
      for (int o = 32; o > 0; o >>= 1) sum += __shfl_xor(sum, o, 64);
      #pragma unroll
      for (int k = 0; k < 8; ++k) bufA[r][lane + 64 * k] = pv[k];
      if (lane == 0) den[r] = sum;
    }
    __syncthreads();

    // D: AV via MFMA (K=512)
    packA(&bufA[0][0], N, N, aPk, t);
    __syncthreads();
    {
      const int col = wid * 16 + (lane & 15);
      const uint4* Vp = (const uint4*)vin + (size_t)b * 64 * 128;
      f32x4 acc = mmaK<16>(aPk, Vp, 128, col, lane);
      if (lane < 16) {
        #pragma unroll
        for (int g = 0; g < 4; ++g) r1[g][col] = acc[g] / den[g];
      }
    }
    __syncthreads();

    // E: WO via MFMA
    packA(&r1[0][0], D, D, aPk, t);
    __syncthreads();
    {
      const int col = wid * 16 + (lane & 15);
      f32x4 acc = mmaK<4>(aPk, WOp, 128, col, lane);
      if (lane < 16) {
        #pragma unroll
        for (int g = 0; g < 4; ++g) r3[g][col] = acc[g];
      }
    }
    __syncthreads();

    // F: residual + LN1
    if (wid < 4) {
      const int r = wid;
      float tv[2];
      #pragma unroll
      for (int k = 0; k < 2; ++k) {
        const int d = lane + 64 * k;
        tv[k] = r3[r][d] + bo[d] + xbuf[(size_t)(row0 + r) * D + d];
      }
      float s = tv[0] + tv[1], sq = tv[0] * tv[0] + tv[1] * tv[1];
      #pragma unroll
      for (int o = 32; o > 0; o >>= 1) { s += __shfl_xor(s, o, 64); sq += __shfl_xor(sq, o, 64); }
      const float mean = s * (1.f / 128.f);
      const float var  = sq * (1.f / 128.f) - mean * mean;
      const float rstd = __frsqrt_rn(var + EPS);
      #pragma unroll
      for (int k = 0; k < 2; ++k) {
        const int d = lane + 64 * k;
        r2[r][d] = (tv[k] - mean) * rstd * g1[d] + b1[d];
      }
    }
    __syncthreads();

    // G: FFN1 via MFMA
    packA(&r2[0][0], D, D, aPk, t);
    __syncthreads();
    {
      #pragma unroll
      for (int i = 0; i < 4; ++i) {
        const int col = (wid * 4 + i) * 16 + (lane & 15);
        f32x4 acc = mmaK<4>(aPk, W1p, 512, col, lane);
        if (lane < 16) {
          const float bb = fb1[col];
          #pragma unroll
          for (int g = 0; g < 4; ++g) bufA[g][col] = fmaxf(acc[g] + bb, 0.f);
        }
      }
    }
    __syncthreads();

    // H: FFN2 via MFMA (K=512)
    packA(&bufA[0][0], F, F, aPk, t);
    __syncthreads();
    {
      const int col = wid * 16 + (lane & 15);
      f32x4 acc = mmaK<16>(aPk, W2p, 128, col, lane);
      if (lane < 16) {
        #pragma unroll
        for (int g = 0; g < 4; ++g) r3[g][col] = acc[g];
      }
    }
    __syncthreads();

    // I: residual + LN2
    if (wid < 4) {
      const int r = wid;
      float tv[2];
      #pragma unroll
      for (int k = 0; k < 2; ++k) {
        const int d = lane + 64 * k;
        tv[k] = r3[r][d] + fb2[d] + r2[r][d];
      }
      float s = tv[0] + tv[1], sq = tv[0] * tv[0] + tv[1] * tv[1];
      #pragma unroll
      for (int o = 32; o > 0; o >>= 1) { s += __shfl_xor(s, o, 64); sq += __shfl_xor(sq, o, 64); }
      const float mean = s * (1.f / 128.f);
      const float var  = sq * (1.f / 128.f) - mean * mean;
      const float rstd = __frsqrt_rn(var + EPS);
      #pragma unroll
      for (int k = 0; k < 2; ++k) {
        const int d = lane + 64 * k;
        const float xn = (tv[k] - mean) * rstd * g2[d] + b2v[d];
        r1[r][d] = xn;
        xbuf[(size_t)(row0 + r) * D + d] = xn;
        if (last) outp[(size_t)(row0 + r) * D + d] = xn;
      }
    }
    __syncthreads();

    // J: QKV for next layer
    if (!last) {
      packA(&r1[0][0], D, D, aPk, t);
      __syncthreads();
      {
        const int col = wid * 16 + (lane & 15);
        #pragma unroll
        for (int m = 0; m < 3; ++m) {
          const uint4* Bp = (const uint4*)(Wb + PB_L0 + (l + 1) * PB_LSTR + m * 8192);
          f32x4 acc = mmaK<4>(aPk, Bp, 128, col, lane);
          if (lane < 16) {
            const float bb = W[(m == 0 ? OFF_BQ : m == 1 ? OFF_BK : OFF_BV) + (l + 1) * D + col];
            if (m == 0) {
              #pragma unroll
              for (int g = 0; g < 4; ++g) qout[(size_t)(row0 + g) * D + col] = acc[g] + bb;
            } else if (m == 1) {
              #pragma unroll
              for (int g = 0; g < 4; ++g) r3[g][col] = acc[g] + bb;
            } else {
              #pragma unroll
              for (int g = 0; g < 4; ++g) r4[g][col] = acc[g] + bb;
            }
          }
        }
      }
      __syncthreads();
      if (t < 64) {
        const int r = t >> 4, e8 = t & 15;
        const float* ks = r3[r];
        uint4 w;
        w.x = pk2(ks[8 * e8 + 0], ks[8 * e8 + 1]);
        w.y = pk2(ks[8 * e8 + 2], ks[8 * e8 + 3]);
        w.z = pk2(ks[8 * e8 + 4], ks[8 * e8 + 5]);
        w.w = pk2(ks[8 * e8 + 6], ks[8 * e8 + 7]);
        ((uint4*)kout)[((size_t)b * 16 + e8) * 512 + (row0 & 511) + r] = w;
      }
      if (t < 128) {
        const int i0 = row0 & 511, j8 = i0 >> 3, h = (i0 >> 2) & 1;
        uint2 w;
        w.x = pk2(r4[0][t], r4[1][t]);
        w.y = pk2(r4[2][t], r4[3][t]);
        *(uint2*)(vout + (((size_t)b * 64 + j8) * 128 + t) * 4 + 2 * h) = w;
      }
      gsync(bar + 2 + l, 256);
    }
  }
}

// ---------------------------------------------------------------------------
extern "C" void kernel_launch(void* const* d_in, const int* in_sizes, int n_in,
                              void* d_out, int out_size, void* d_ws, size_t ws_size,
                              hipStream_t stream) {
  // ws layout (4-byte units)
  int*   flags = (int*)d_ws;                 // [4..7] = grid-barrier counters
  int*   bar   = flags + 4;
  int*   mbuf  = flags + 16;
  float* xbuf  = (float*)d_ws + 1040;
  float* q0    = xbuf + NROW * D;
  float* q1    = q0 + NROW * D;
  u32*   kT0   = (u32*)(q1 + NROW * D);      // [B][16][512] uint4
  u32*   kT1   = kT0 + 65536;
  u32*   vT0   = kT1 + 65536;                // [B][64][128] uint4
  u32*   vT1   = vT0 + 65536;
  float* W     = (float*)(vT1 + 65536);
  u32*   Wb    = (u32*)(W + W_TOTAL);

  PrepArgs pa;
  {
    const NEnt nrm[19] = {
      {d_in[1],  OFF_PRE_W,  256}, {d_in[2],  OFF_PRE_B, 128},
      {d_in[4],  OFF_PROJ_B, 128},
      {d_in[6],  OFF_BN_G,   128}, {d_in[7],  OFF_BN_B,  128},
      {d_in[8],  OFF_BN_M,   128}, {d_in[9],  OFF_BN_V,  128},
      {d_in[11], OFF_OUT_B2, 128}, {d_in[12], OFF_PE,  16384},
      {d_in[14], OFF_BQ,     384}, {d_in[16], OFF_BK,    384},
      {d_in[18], OFF_BV,     384}, {d_in[20], OFF_BO,    384},
      {d_in[21], OFF_LN1G,   384}, {d_in[22], OFF_LN1B,  384},
      {d_in[23], OFF_LN2G,   384}, {d_in[24], OFF_LN2B,  384},
      {d_in[26], OFF_FB1,   1536}, {d_in[28], OFF_FB2,   384}};
    for (int i = 0; i < 19; ++i) pa.nrm[i] = nrm[i];

    pa.pk[0] = {d_in[3], d_in[3], 0, 16384, PB_PROJ, 7, 0};
    pa.pk[1] = {d_in[5],  nullptr, 0, 0, PB_OW1, 7, 2048};
    pa.pk[2] = {d_in[10], nullptr, 0, 0, PB_OW2, 7, 4096};
    for (int l = 0; l < 3; ++l) {
      const int lb = PB_L0 + l * PB_LSTR;
      const int cl = 6144 + l * 24576;
      pa.pk[3 + 6 * l + 0] = {d_in[13], nullptr, l * 16384, 0, lb,          7, cl};
      pa.pk[3 + 6 * l + 1] = {d_in[15], nullptr, l * 16384, 0, lb + 8192,   7, cl + 2048};
      pa.pk[3 + 6 * l + 2] = {d_in[17], nullptr, l * 16384, 0, lb + 16384,  7, cl + 4096};
      pa.pk[3 + 6 * l + 3] = {d_in[19], nullptr, l * 16384, 0, lb + PB_WO,  7, cl + 6144};
      pa.pk[3 + 6 * l + 4] = {d_in[25], nullptr, l * 65536, 0, lb + PB_FW1, 9, cl + 8192};
      pa.pk[3 + 6 * l + 5] = {d_in[27], nullptr, l * 65536, 0, lb + PB_FW2, 7, cl + 16384};
    }
  }
  const int* agent_id = (const int*)d_in[30];

  // zero the grid-barrier counters (in-graph, replay-safe)
  hipMemsetAsync((void*)bar, 0, 4 * sizeof(int), stream);

  k_all<<<256, 512, 0, stream>>>(pa, d_in[0], d_in[9], d_in[29], agent_id,
                                 bar, mbuf, xbuf, q0, q1, kT0, kT1, vT0, vT1,
                                 W, Wb, (float*)d_out);
}

// Round 10
// 135.421 us; speedup vs baseline: 1.3924x; 1.3924x over previous
//
#include <hip/hip_runtime.h>
#include <hip/hip_bf16.h>

typedef unsigned short u16;
typedef unsigned int u32;
typedef unsigned char u8;
typedef __attribute__((ext_vector_type(8))) short bf16x8;
typedef __attribute__((ext_vector_type(4))) float f32x4;

#define DEV __device__ __forceinline__

DEV float bf2f(u16 u) { union { u32 i; float f; } c; c.i = ((u32)u) << 16; return c.f; }
DEV u16 f2bf(float f) {  // round-to-nearest-even
  union { float f; u32 i; } c; c.f = f;
  u32 r = c.i + 0x7FFFu + ((c.i >> 16) & 1u);
  return (u16)(r >> 16);
}
DEV u32 pk2(float lo, float hi) { return (u32)f2bf(lo) | ((u32)f2bf(hi) << 16); }
DEV float rdsrc(const void* p, int e, int isb) {
  return isb ? bf2f(((const u16*)p)[e]) : ((const float*)p)[e];
}
DEV bf16x8 as_bf(uint4 v) { union { uint4 u; bf16x8 h; } c; c.u = v; return c.h; }

static constexpr int B = 2, N = 512, D = 128, F = 512;
static constexpr int NROW = B * N;  // 1024
static constexpr float EPS = 1e-5f;
static constexpr float NEG = -1e9f;
static constexpr float SCALE = 0.08838834764831845f;  // 1/sqrt(128)

// ---- fp32 small-weight region offsets ------------------------------------
#define OFF_PRE_W   0
#define OFF_PRE_B   256
#define OFF_PROJ_B  33152
#define OFF_BN_G    49664
#define OFF_BN_B    49792
#define OFF_BN_M    49920
#define OFF_BN_V    50048
#define OFF_OUT_B2  66560
#define OFF_PE      66688
#define OFF_BQ      132224
#define OFF_BK      181760
#define OFF_BV      231296
#define OFF_BO      280832
#define OFF_LN1G    281216
#define OFF_LN1B    281600
#define OFF_LN2G    281984
#define OFF_LN2B    282368
#define OFF_FB1     479360
#define OFF_FB2     677504
#define W_TOTAL     677888

// ---- packed-bf16 weight region (u32 units; [e8][col] uint4 of 8 K-elems) --
static constexpr int PB_PROJ = 0;
static constexpr int PB_OW1  = 8192;
static constexpr int PB_OW2  = 16384;
static constexpr int PB_L0   = 24576;
static constexpr int PB_LSTR = 98304;
static constexpr int PB_WO   = 24576;
static constexpr int PB_FW1  = 32768;
static constexpr int PB_FW2  = 65536;
static constexpr int PTOT    = 79872;   // total uint4 pack entries

struct NEnt { const void* s; int off, n; };
struct PEnt { const void* s1; const void* s2; int o1, o2, dst, lgn, cum; };
struct PrepArgs { NEnt nrm[19]; PEnt pk[21]; };

// ---------------------------------------------------------------------------
// Grid barrier — FIXED vs round 9: the spin uses a RELAXED agent-scope load
// (performed at the coherence point, sees remote updates, but emits NO
// buffer_inv), and a SINGLE acquire fence after exit. Round 9's per-iteration
// ACQUIRE load invalidated the XCD's L1+L2 every ~200ns while sibling blocks
// streamed weights -> 2.5x slowdown (k_all 197us, VALUBusy 2.8%).
// ---------------------------------------------------------------------------
DEV void gsync(int* c, int nblk) {
  __syncthreads();
  if (threadIdx.x == 0) {
    // release: publish this block's writes (wb) + arrive
    __hip_atomic_fetch_add(c, 1, __ATOMIC_RELEASE, __HIP_MEMORY_SCOPE_AGENT);
    // relaxed spin: no cache invalidation per poll
    while (__hip_atomic_load(c, __ATOMIC_RELAXED, __HIP_MEMORY_SCOPE_AGENT) < nblk)
      __builtin_amdgcn_s_sleep(2);
    // one acquire: invalidate L1/L2 once so post-barrier reads see remote data
    __builtin_amdgcn_fence(__ATOMIC_ACQUIRE, "agent");
  }
  __syncthreads();
}

// ---------------------------------------------------------------------------
// MFMA helpers (round-8 verified): A = 4 real rows (rows 4..15 zero) packed
// [e8][16] uint4 in LDS; B = [e8][ncol] uint4. D rows 0..3 -> lanes 0..15,
// regs 0..3 (gfx950 C/D map: col=lane&15, row=(lane>>4)*4+reg).
// ---------------------------------------------------------------------------
template<int KT>
DEV f32x4 mmaK(const uint4* __restrict__ aPk, const uint4* __restrict__ Bp,
               int ncol, int col, int lane) {
  f32x4 acc = {0.f, 0.f, 0.f, 0.f};
  const int sub = lane >> 4;
  #pragma unroll
  for (int kt = 0; kt < KT; ++kt) {
    const int e8 = kt * 4 + sub;
    acc = __builtin_amdgcn_mfma_f32_16x16x32_bf16(
        as_bf(aPk[e8 * 16 + (lane & 15)]),
        as_bf(Bp[(size_t)e8 * ncol + col]),
        acc, 0, 0, 0);
  }
  return acc;
}

DEV void packA(const float* __restrict__ src, int ld, int K,
               uint4* __restrict__ aPk, int t) {
  const int n = (K >> 3) * 4;
  for (int i = t; i < n; i += 512) {
    const int e8 = i >> 2, r = i & 3;
    const float* s = src + r * ld + e8 * 8;
    uint4 w;
    w.x = pk2(s[0], s[1]); w.y = pk2(s[2], s[3]);
    w.z = pk2(s[4], s[5]); w.w = pk2(s[6], s[7]);
    aPk[e8 * 16 + r] = w;
  }
}

// ---------------------------------------------------------------------------
// k_all: fused prep + relchain/QKV0 + 3 transformer layers; grid barriers
// between stages. 256 blocks x 512 threads.
// ---------------------------------------------------------------------------
__global__ __launch_bounds__(512) void k_all(PrepArgs pa,
    const void* __restrict__ relv, const void* __restrict__ bnv,
    const void* __restrict__ maskp, const int* __restrict__ agent_id,
    int* __restrict__ bar, int* __restrict__ mbuf,
    float* __restrict__ xbuf, float* __restrict__ q0, float* __restrict__ q1,
    u32* __restrict__ kT0, u32* __restrict__ kT1,
    u32* __restrict__ vT0, u32* __restrict__ vT1,
    float* __restrict__ W, u32* __restrict__ Wb, float* __restrict__ outp)
{
  const int t = threadIdx.x;            // 0..511
  const int blk = blockIdx.x;           // 0..255
  const int row0 = blk * 4;
  const int b = row0 >> 9;
  const int wid = t >> 6;
  const int lane = t & 63;

  // Phase-overlapped shared memory (~37 KB)
  __shared__ float bufA[4][512];                 // p / hs / pB(relq)
  __shared__ float r0[4][128], r1[4][128], r2[4][128], r3[4][128], r4[4][128];
  __shared__ uint4 aPk[1024];
  __shared__ float wred[8][9];
  __shared__ float sT0[4], sT1[4];
  __shared__ float sMt, den[4];
  __shared__ int s_nb, s_m4, s_m2;

  // =========================== stage 0: prep ==============================
  if (t == 0) { s_nb = 0; s_m4 = 0; s_m2 = 0; }
  __syncthreads();
  if (t < 64) {
    const u32 w = ((const u32*)bnv)[t];
    if (((w >> 8) & 0xFFu) != 0x3Fu || ((w >> 24) & 0xFFu) != 0x3Fu)
      atomicOr(&s_nb, 1);
  }
  __syncthreads();
  const int isb = s_nb ? 0 : 1;

  // norm small tensors to fp32 W
  for (int ten = 0; ten < 19; ++ten) {
    const NEnt E = pa.nrm[ten];
    for (int e = blk * 512 + t; e < E.n; e += 256 * 512)
      W[E.off + e] = rdsrc(E.s, e, isb);
  }
  // pack big weights (bf16, [e8][col] uint4)
  for (int g = blk * 512 + t; g < PTOT; g += 256 * 512) {
    int ei = 0;
    #pragma unroll
    for (int k = 1; k < 21; ++k) if (g >= pa.pk[k].cum) ei = k;
    const PEnt E = pa.pk[ei];
    const int li = g - E.cum;
    const int e8 = li >> E.lgn, c = li & ((1 << E.lgn) - 1);
    float f[8];
    #pragma unroll
    for (int i = 0; i < 8; ++i) {
      const int si = ((e8 * 8 + i) << E.lgn) + c;
      f[i] = rdsrc(E.s1, E.o1 + si, isb);
      if (E.s2) f[i] += rdsrc(E.s2, E.o2 + si, isb);
    }
    uint4 w;
    w.x = pk2(f[0], f[1]); w.y = pk2(f[2], f[3]);
    w.z = pk2(f[4], f[5]); w.w = pk2(f[6], f[7]);
    ((uint4*)(Wb + E.dst))[li] = w;
  }
  // mask normalization (block 255)
  if (blk == 255) {
    if (t < 256) {
      const u32 w = ((const u32*)maskp)[t];
      if (!(w == 0u || w == 1u || w == 0x3F800000u)) atomicOr(&s_m4, 1);
      if (!(w == 0u || w == 1u || w == 0x10000u || w == 0x10001u ||
            w == 0x3F80u || w == 0x3F800000u || w == 0x3F803F80u)) atomicOr(&s_m2, 1);
    }
    __syncthreads();
    const int mode = (!s_m4) ? 4 : ((!s_m2) ? 2 : 1);
    #pragma unroll
    for (int k = 0; k < 2; ++k) {
      const int e = k * 512 + t;
      int v;
      if (mode == 4)      v = (((const u32*)maskp)[e] != 0u);
      else if (mode == 2) v = (((const u16*)maskp)[e] != 0);
      else                v = (((const u8*)maskp)[e]  != 0);
      mbuf[e] = v;
    }
  }
  gsync(bar + 0, 256);

  // ====================== stage 1: relchain + QKV(0) ======================
  {
    float s0[4] = {0, 0, 0, 0}, s1[4] = {0, 0, 0, 0}, cnt;
    {
      const int j = t;
      const float m = (float)mbuf[b * N + j];
      cnt = m;
      if (isb) {
        const u32* rel2 = (const u32*)relv;
        #pragma unroll
        for (int r = 0; r < 4; ++r) {
          const u32 u = rel2[(size_t)(row0 + r) * N + j];
          s0[r] += m * bf2f((u16)(u & 0xFFFFu));
          s1[r] += m * bf2f((u16)(u >> 16));
        }
      } else {
        const float2* relf = (const float2*)relv;
        #pragma unroll
        for (int r = 0; r < 4; ++r) {
          const float2 u = relf[(size_t)(row0 + r) * N + j];
          s0[r] += m * u.x; s1[r] += m * u.y;
        }
      }
    }
    {
      const uint4 z = {0u, 0u, 0u, 0u};
      aPk[t] = z; aPk[t + 512] = z;
    }
    #pragma unroll
    for (int o = 32; o > 0; o >>= 1) {
      #pragma unroll
      for (int r = 0; r < 4; ++r) {
        s0[r] += __shfl_xor(s0[r], o, 64);
        s1[r] += __shfl_xor(s1[r], o, 64);
      }
      cnt += __shfl_xor(cnt, o, 64);
    }
    if ((t & 63) == 0) {
      #pragma unroll
      for (int r = 0; r < 4; ++r) { wred[wid][r] = s0[r]; wred[wid][4 + r] = s1[r]; }
      wred[wid][8] = cnt;
    }
    __syncthreads();
    if (t < 4) {
      float a0 = 0, a1 = 0;
      #pragma unroll
      for (int w = 0; w < 8; ++w) { a0 += wred[w][t]; a1 += wred[w][4 + t]; }
      sT0[t] = a0; sT1[t] = a1;
    }
    if (t == 8) {
      float c = 0;
      #pragma unroll
      for (int w = 0; w < 8; ++w) c += wred[w][8];
      sMt = c;
    }
    __syncthreads();

    // P2: pooled
    {
      const int r = t >> 7, c = t & 127;
      const int mi = mbuf[row0 + r];
      r0[r][c] = mi ? (sT0[r] * W[OFF_PRE_W + c] + sT1[r] * W[OFF_PRE_W + D + c]) / sMt
                      + W[OFF_PRE_B + c]
                    : 0.f;
    }
    __syncthreads();

    // P3: pooled @ (P1+P2)
    packA(&r0[0][0], D, D, aPk, t);
    __syncthreads();
    {
      const int col = wid * 16 + (lane & 15);
      f32x4 acc = mmaK<4>(aPk, (const uint4*)(Wb + PB_PROJ), 128, col, lane);
      if (lane < 16) {
        #pragma unroll
        for (int g = 0; g < 4; ++g) r4[g][col] = acc[g];
      }
    }
    __syncthreads();
    {
      const int r = t >> 7, d = t & 127;
      r1[r][d] = mbuf[row0 + r] ? r4[r][d] + W[OFF_PROJ_B + d] : 0.f;
    }
    __syncthreads();

    // P4: z @ out_w1; bn; relu
    packA(&r1[0][0], D, D, aPk, t);
    __syncthreads();
    {
      const int col = wid * 16 + (lane & 15);
      f32x4 acc = mmaK<4>(aPk, (const uint4*)(Wb + PB_OW1), 128, col, lane);
      if (lane < 16) {
        #pragma unroll
        for (int g = 0; g < 4; ++g) r4[g][col] = acc[g];
      }
    }
    __syncthreads();
    {
      const int r = t >> 7, d = t & 127;
      const float hb = (r4[r][d] - W[OFF_BN_M + d]) * __frsqrt_rn(W[OFF_BN_V + d] + EPS)
                       * W[OFF_BN_G + d] + W[OFF_BN_B + d];
      r2[r][d] = fmaxf(hb, 0.f);
    }
    __syncthreads();

    // P5: relu_h @ out_w2 + out_b2 + pe
    packA(&r2[0][0], D, D, aPk, t);
    __syncthreads();
    {
      const int col = wid * 16 + (lane & 15);
      f32x4 acc = mmaK<4>(aPk, (const uint4*)(Wb + PB_OW2), 128, col, lane);
      if (lane < 16) {
        #pragma unroll
        for (int g = 0; g < 4; ++g) r4[g][col] = acc[g];
      }
    }
    __syncthreads();
    {
      const int r = t >> 7, d = t & 127;
      const int aid = agent_id[row0 + r];
      const float x0 = r4[r][d] + W[OFF_OUT_B2 + d] + W[OFF_PE + aid * D + d];
      r3[r][d] = x0;
      xbuf[(size_t)(row0 + r) * D + d] = x0;
    }
    __syncthreads();

    // P6: QKV layer 0 (K -> r4, V -> bufA[.][0..127])
    packA(&r3[0][0], D, D, aPk, t);
    __syncthreads();
    {
      const int col = wid * 16 + (lane & 15);
      #pragma unroll
      for (int m = 0; m < 3; ++m) {
        f32x4 acc = mmaK<4>(aPk, (const uint4*)(Wb + PB_L0 + m * 8192), 128, col, lane);
        if (lane < 16) {
          const float bb = W[(m == 0 ? OFF_BQ : m == 1 ? OFF_BK : OFF_BV) + col];
          if (m == 0) {
            #pragma unroll
            for (int g = 0; g < 4; ++g) q0[(size_t)(row0 + g) * D + col] = acc[g] + bb;
          } else if (m == 1) {
            #pragma unroll
            for (int g = 0; g < 4; ++g) r4[g][col] = acc[g] + bb;
          } else {
            #pragma unroll
            for (int g = 0; g < 4; ++g) bufA[g][col] = acc[g] + bb;
          }
        }
      }
    }
    __syncthreads();
    if (t < 64) {   // packed K^T: [b][e8][j] uint4
      const int r = t >> 4, e8 = t & 15;
      const float* ks = r4[r];
      uint4 w;
      w.x = pk2(ks[8 * e8 + 0], ks[8 * e8 + 1]);
      w.y = pk2(ks[8 * e8 + 2], ks[8 * e8 + 3]);
      w.z = pk2(ks[8 * e8 + 4], ks[8 * e8 + 5]);
      w.w = pk2(ks[8 * e8 + 6], ks[8 * e8 + 7]);
      ((uint4*)kT0)[((size_t)b * 16 + e8) * 512 + (row0 & 511) + r] = w;
    }
    if (t < 128) {  // packed V: [b][j8][d] uint4 (half per block)
      const int i0 = row0 & 511, j8 = i0 >> 3, h = (i0 >> 2) & 1;
      uint2 w;
      w.x = pk2(bufA[0][t], bufA[1][t]);
      w.y = pk2(bufA[2][t], bufA[3][t]);
      *(uint2*)(vT0 + (((size_t)b * 64 + j8) * 128 + t) * 4 + 2 * h) = w;
    }
  }
  gsync(bar + 1, 256);

  // ========================= stages 2-4: layers ===========================
  for (int l = 0; l < 3; ++l) {
    const int last = (l == 2);
    const float* qin = (l & 1) ? q1 : q0;
    float*       qout = (l & 1) ? q0 : q1;
    const u32*   kin = (l & 1) ? kT1 : kT0;
    u32*         kout = (l & 1) ? kT0 : kT1;
    const u32*   vin = (l & 1) ? vT1 : vT0;
    u32*         vout = (l & 1) ? vT0 : vT1;

    const uint4* WOp = (const uint4*)(Wb + PB_L0 + l * PB_LSTR + PB_WO);
    const uint4* W1p = (const uint4*)(Wb + PB_L0 + l * PB_LSTR + PB_FW1);
    const uint4* W2p = (const uint4*)(Wb + PB_L0 + l * PB_LSTR + PB_FW2);
    const float* bo  = W + OFF_BO  + l * D;
    const float* g1  = W + OFF_LN1G + l * D;
    const float* b1  = W + OFF_LN1B + l * D;
    const float* fb1 = W + OFF_FB1 + l * F;
    const float* fb2 = W + OFF_FB2 + l * D;
    const float* g2  = W + OFF_LN2G + l * D;
    const float* b2v = W + OFF_LN2B + l * D;

    // A: load Q rows pre-scaled
    {
      const int r = t >> 7, d = t & 127;
      r0[r][d] = qin[(size_t)(row0 + r) * D + d] * SCALE;
    }
    __syncthreads();

    // B: scores via MFMA
    packA(&r0[0][0], D, D, aPk, t);
    __syncthreads();
    {
      const uint4* Kp = (const uint4*)kin + (size_t)b * 16 * 512;
      #pragma unroll
      for (int i = 0; i < 4; ++i) {
        const int col = (wid * 4 + i) * 16 + (lane & 15);
        f32x4 acc = mmaK<4>(aPk, Kp, 512, col, lane);
        if (lane < 16) {
          const float bias = mbuf[b * N + col] ? 0.f : NEG;
          #pragma unroll
          for (int g = 0; g < 4; ++g) bufA[g][col] = acc[g] + bias;
        }
      }
    }
    __syncthreads();

    // C: softmax — wave w handles row w
    if (wid < 4) {
      const int r = wid;
      float pv[8];
      float mx = -1e30f;
      #pragma unroll
      for (int k = 0; k < 8; ++k) { pv[k] = bufA[r][lane + 64 * k]; mx = fmaxf(mx, pv[k]); }
      #pragma unroll
      for (int o = 32; o > 0; o >>= 1) mx = fmaxf(mx, __shfl_xor(mx, o, 64));
      float sum = 0.f;
      #pragma unroll
      for (int k = 0; k < 8; ++k) { pv[k] = __expf(pv[k] - mx); sum += pv[k]; }
      #pragma unroll
      for (int o = 32; o > 0; o >>= 1) sum += __shfl_xor(sum, o, 64);
      #pragma unroll
      for (int k = 0; k < 8; ++k) bufA[r][lane + 64 * k] = pv[k];
      if (lane == 0) den[r] = sum;
    }
    __syncthreads();

    // D: AV via MFMA (K=512)
    packA(&bufA[0][0], N, N, aPk, t);
    __syncthreads();
    {
      const int col = wid * 16 + (lane & 15);
      const uint4* Vp = (const uint4*)vin + (size_t)b * 64 * 128;
      f32x4 acc = mmaK<16>(aPk, Vp, 128, col, lane);
      if (lane < 16) {
        #pragma unroll
        for (int g = 0; g < 4; ++g) r1[g][col] = acc[g] / den[g];
      }
    }
    __syncthreads();

    // E: WO via MFMA
    packA(&r1[0][0], D, D, aPk, t);
    __syncthreads();
    {
      const int col = wid * 16 + (lane & 15);
      f32x4 acc = mmaK<4>(aPk, WOp, 128, col, lane);
      if (lane < 16) {
        #pragma unroll
        for (int g = 0; g < 4; ++g) r3[g][col] = acc[g];
      }
    }
    __syncthreads();

    // F: residual + LN1
    if (wid < 4) {
      const int r = wid;
      float tv[2];
      #pragma unroll
      for (int k = 0; k < 2; ++k) {
        const int d = lane + 64 * k;
        tv[k] = r3[r][d] + bo[d] + xbuf[(size_t)(row0 + r) * D + d];
      }
      float s = tv[0] + tv[1], sq = tv[0] * tv[0] + tv[1] * tv[1];
      #pragma unroll
      for (int o = 32; o > 0; o >>= 1) { s += __shfl_xor(s, o, 64); sq += __shfl_xor(sq, o, 64); }
      const float mean = s * (1.f / 128.f);
      const float var  = sq * (1.f / 128.f) - mean * mean;
      const float rstd = __frsqrt_rn(var + EPS);
      #pragma unroll
      for (int k = 0; k < 2; ++k) {
        const int d = lane + 64 * k;
        r2[r][d] = (tv[k] - mean) * rstd * g1[d] + b1[d];
      }
    }
    __syncthreads();

    // G: FFN1 via MFMA
    packA(&r2[0][0], D, D, aPk, t);
    __syncthreads();
    {
      #pragma unroll
      for (int i = 0; i < 4; ++i) {
        const int col = (wid * 4 + i) * 16 + (lane & 15);
        f32x4 acc = mmaK<4>(aPk, W1p, 512, col, lane);
        if (lane < 16) {
          const float bb = fb1[col];
          #pragma unroll
          for (int g = 0; g < 4; ++g) bufA[g][col] = fmaxf(acc[g] + bb, 0.f);
        }
      }
    }
    __syncthreads();

    // H: FFN2 via MFMA (K=512)
    packA(&bufA[0][0], F, F, aPk, t);
    __syncthreads();
    {
      const int col = wid * 16 + (lane & 15);
      f32x4 acc = mmaK<16>(aPk, W2p, 128, col, lane);
      if (lane < 16) {
        #pragma unroll
        for (int g = 0; g < 4; ++g) r3[g][col] = acc[g];
      }
    }
    __syncthreads();

    // I: residual + LN2
    if (wid < 4) {
      const int r = wid;
      float tv[2];
      #pragma unroll
      for (int k = 0; k < 2; ++k) {
        const int d = lane + 64 * k;
        tv[k] = r3[r][d] + fb2[d] + r2[r][d];
      }
      float s = tv[0] + tv[1], sq = tv[0] * tv[0] + tv[1] * tv[1];
      #pragma unroll
      for (int o = 32; o > 0; o >>= 1) { s += __shfl_xor(s, o, 64); sq += __shfl_xor(sq, o, 64); }
      const float mean = s * (1.f / 128.f);
      const float var  = sq * (1.f / 128.f) - mean * mean;
      const float rstd = __frsqrt_rn(var + EPS);
      #pragma unroll
      for (int k = 0; k < 2; ++k) {
        const int d = lane + 64 * k;
        const float xn = (tv[k] - mean) * rstd * g2[d] + b2v[d];
        r1[r][d] = xn;
        xbuf[(size_t)(row0 + r) * D + d] = xn;
        if (last) outp[(size_t)(row0 + r) * D + d] = xn;
      }
    }
    __syncthreads();

    // J: QKV for next layer
    if (!last) {
      packA(&r1[0][0], D, D, aPk, t);
      __syncthreads();
      {
        const int col = wid * 16 + (lane & 15);
        #pragma unroll
        for (int m = 0; m < 3; ++m) {
          const uint4* Bp = (const uint4*)(Wb + PB_L0 + (l + 1) * PB_LSTR + m * 8192);
          f32x4 acc = mmaK<4>(aPk, Bp, 128, col, lane);
          if (lane < 16) {
            const float bb = W[(m == 0 ? OFF_BQ : m == 1 ? OFF_BK : OFF_BV) + (l + 1) * D + col];
            if (m == 0) {
              #pragma unroll
              for (int g = 0; g < 4; ++g) qout[(size_t)(row0 + g) * D + col] = acc[g] + bb;
            } else if (m == 1) {
              #pragma unroll
              for (int g = 0; g < 4; ++g) r3[g][col] = acc[g] + bb;
            } else {
              #pragma unroll
              for (int g = 0; g < 4; ++g) r4[g][col] = acc[g] + bb;
            }
          }
        }
      }
      __syncthreads();
      if (t < 64) {
        const int r = t >> 4, e8 = t & 15;
        const float* ks = r3[r];
        uint4 w;
        w.x = pk2(ks[8 * e8 + 0], ks[8 * e8 + 1]);
        w.y = pk2(ks[8 * e8 + 2], ks[8 * e8 + 3]);
        w.z = pk2(ks[8 * e8 + 4], ks[8 * e8 + 5]);
        w.w = pk2(ks[8 * e8 + 6], ks[8 * e8 + 7]);
        ((uint4*)kout)[((size_t)b * 16 + e8) * 512 + (row0 & 511) + r] = w;
      }
      if (t < 128) {
        const int i0 = row0 & 511, j8 = i0 >> 3, h = (i0 >> 2) & 1;
        uint2 w;
        w.x = pk2(r4[0][t], r4[1][t]);
        w.y = pk2(r4[2][t], r4[3][t]);
        *(uint2*)(vout + (((size_t)b * 64 + j8) * 128 + t) * 4 + 2 * h) = w;
      }
      gsync(bar + 2 + l, 256);
    }
  }
}

// ---------------------------------------------------------------------------
extern "C" void kernel_launch(void* const* d_in, const int* in_sizes, int n_in,
                              void* d_out, int out_size, void* d_ws, size_t ws_size,
                              hipStream_t stream) {
  // ws layout (4-byte units)
  int*   flags = (int*)d_ws;                 // [4..7] = grid-barrier counters
  int*   bar   = flags + 4;
  int*   mbuf  = flags + 16;
  float* xbuf  = (float*)d_ws + 1040;
  float* q0    = xbuf + NROW * D;
  float* q1    = q0 + NROW * D;
  u32*   kT0   = (u32*)(q1 + NROW * D);      // [B][16][512] uint4
  u32*   kT1   = kT0 + 65536;
  u32*   vT0   = kT1 + 65536;                // [B][64][128] uint4
  u32*   vT1   = vT0 + 65536;
  float* W     = (float*)(vT1 + 65536);
  u32*   Wb    = (u32*)(W + W_TOTAL);

  PrepArgs pa;
  {
    const NEnt nrm[19] = {
      {d_in[1],  OFF_PRE_W,  256}, {d_in[2],  OFF_PRE_B, 128},
      {d_in[4],  OFF_PROJ_B, 128},
      {d_in[6],  OFF_BN_G,   128}, {d_in[7],  OFF_BN_B,  128},
      {d_in[8],  OFF_BN_M,   128}, {d_in[9],  OFF_BN_V,  128},
      {d_in[11], OFF_OUT_B2, 128}, {d_in[12], OFF_PE,  16384},
      {d_in[14], OFF_BQ,     384}, {d_in[16], OFF_BK,    384},
      {d_in[18], OFF_BV,     384}, {d_in[20], OFF_BO,    384},
      {d_in[21], OFF_LN1G,   384}, {d_in[22], OFF_LN1B,  384},
      {d_in[23], OFF_LN2G,   384}, {d_in[24], OFF_LN2B,  384},
      {d_in[26], OFF_FB1,   1536}, {d_in[28], OFF_FB2,   384}};
    for (int i = 0; i < 19; ++i) pa.nrm[i] = nrm[i];

    pa.pk[0] = {d_in[3], d_in[3], 0, 16384, PB_PROJ, 7, 0};
    pa.pk[1] = {d_in[5],  nullptr, 0, 0, PB_OW1, 7, 2048};
    pa.pk[2] = {d_in[10], nullptr, 0, 0, PB_OW2, 7, 4096};
    for (int l = 0; l < 3; ++l) {
      const int lb = PB_L0 + l * PB_LSTR;
      const int cl = 6144 + l * 24576;
      pa.pk[3 + 6 * l + 0] = {d_in[13], nullptr, l * 16384, 0, lb,          7, cl};
      pa.pk[3 + 6 * l + 1] = {d_in[15], nullptr, l * 16384, 0, lb + 8192,   7, cl + 2048};
      pa.pk[3 + 6 * l + 2] = {d_in[17], nullptr, l * 16384, 0, lb + 16384,  7, cl + 4096};
      pa.pk[3 + 6 * l + 3] = {d_in[19], nullptr, l * 16384, 0, lb + PB_WO,  7, cl + 6144};
      pa.pk[3 + 6 * l + 4] = {d_in[25], nullptr, l * 65536, 0, lb + PB_FW1, 9, cl + 8192};
      pa.pk[3 + 6 * l + 5] = {d_in[27], nullptr, l * 65536, 0, lb + PB_FW2, 7, cl + 16384};
    }
  }
  const int* agent_id = (const int*)d_in[30];

  // zero the grid-barrier counters (in-graph, replay-safe)
  hipMemsetAsync((void*)bar, 0, 4 * sizeof(int), stream);

  k_all<<<256, 512, 0, stream>>>(pa, d_in[0], d_in[9], d_in[29], agent_id,
                                 bar, mbuf, xbuf, q0, q1, kT0, kT1, vT0, vT1,
                                 W, Wb, (float*)d_out);
}

// Round 11
// 67.797 us; speedup vs baseline: 2.7812x; 1.9974x over previous
//
#include <hip/hip_runtime.h>
#include <hip/hip_bf16.h>

typedef unsigned short u16;
typedef unsigned int u32;
typedef unsigned char u8;
typedef __attribute__((ext_vector_type(8))) short bf16x8;
typedef __attribute__((ext_vector_type(4))) float f32x4;

#define DEV __device__ __forceinline__

DEV float bf2f(u16 u) { union { u32 i; float f; } c; c.i = ((u32)u) << 16; return c.f; }
DEV u16 f2bf(float f) {  // round-to-nearest-even
  union { float f; u32 i; } c; c.f = f;
  u32 r = c.i + 0x7FFFu + ((c.i >> 16) & 1u);
  return (u16)(r >> 16);
}
DEV u32 pk2(float lo, float hi) { return (u32)f2bf(lo) | ((u32)f2bf(hi) << 16); }
DEV float rdsrc(const void* p, int e, int isb) {
  return isb ? bf2f(((const u16*)p)[e]) : ((const float*)p)[e];
}
DEV bf16x8 as_bf(uint4 v) { union { uint4 u; bf16x8 h; } c; c.u = v; return c.h; }

static constexpr int B = 2, N = 512, D = 128, F = 512;
static constexpr int NROW = B * N;  // 1024
static constexpr float EPS = 1e-5f;
static constexpr float NEG = -1e9f;
static constexpr float SCALE = 0.08838834764831845f;  // 1/sqrt(128)

// ---- fp32 small-weight region offsets ------------------------------------
#define OFF_PRE_W   0
#define OFF_PRE_B   256
#define OFF_PROJ_B  33152
#define OFF_BN_G    49664
#define OFF_BN_B    49792
#define OFF_BN_M    49920
#define OFF_BN_V    50048
#define OFF_OUT_B2  66560
#define OFF_PE      66688
#define OFF_BQ      132224
#define OFF_BK      181760
#define OFF_BV      231296
#define OFF_BO      280832
#define OFF_LN1G    281216
#define OFF_LN1B    281600
#define OFF_LN2G    281984
#define OFF_LN2B    282368
#define OFF_FB1     479360
#define OFF_FB2     677504
#define W_TOTAL     677888

// ---- packed-bf16 weight region (u32 units; [e8][col] uint4 of 8 K-elems) --
static constexpr int PB_PROJ = 0;
static constexpr int PB_OW1  = 8192;
static constexpr int PB_OW2  = 16384;
static constexpr int PB_L0   = 24576;
static constexpr int PB_LSTR = 98304;
static constexpr int PB_WO   = 24576;
static constexpr int PB_FW1  = 32768;
static constexpr int PB_FW2  = 65536;
static constexpr int PTOT    = 79872;   // total uint4 pack entries

struct NEnt { const void* s; int off, n; };
struct PEnt { const void* s1; const void* s2; int o1, o2, dst, lgn, cum; };
struct PrepArgs { NEnt nrm[19]; PEnt pk[21]; };

// ---------------------------------------------------------------------------
// MFMA helpers (round-8 verified): A = 4 real rows (rows 4..15 zero) packed
// [e8][16] uint4 in LDS; B = [e8][ncol] uint4. D rows 0..3 -> lanes 0..15,
// regs 0..3 (gfx950 C/D map: col=lane&15, row=(lane>>4)*4+reg).
// mmaKo adds a K-offset so two wave-halves can split a long K.
// ---------------------------------------------------------------------------
template<int KT>
DEV f32x4 mmaKo(const uint4* __restrict__ aPk, const uint4* __restrict__ Bp,
                int ncol, int col, int lane, int kt0) {
  f32x4 acc = {0.f, 0.f, 0.f, 0.f};
  const int sub = lane >> 4;
  #pragma unroll
  for (int kt = 0; kt < KT; ++kt) {
    const int e8 = (kt0 + kt) * 4 + sub;
    acc = __builtin_amdgcn_mfma_f32_16x16x32_bf16(
        as_bf(aPk[e8 * 16 + (lane & 15)]),
        as_bf(Bp[(size_t)e8 * ncol + col]),
        acc, 0, 0, 0);
  }
  return acc;
}

DEV void packA(const float* __restrict__ src, int ld, int K,
               uint4* __restrict__ aPk, int t, int nthr) {
  const int n = (K >> 3) * 4;
  for (int i = t; i < n; i += nthr) {
    const int e8 = i >> 2, r = i & 3;
    const float* s = src + r * ld + e8 * 8;
    uint4 w;
    w.x = pk2(s[0], s[1]); w.y = pk2(s[2], s[3]);
    w.z = pk2(s[4], s[5]); w.w = pk2(s[6], s[7]);
    aPk[e8 * 16 + r] = w;
  }
}

// ---------------------------------------------------------------------------
// k_prep (512 blocks): 0..15 norm small tensors; 16..510 build packed
// weights; 511 normalizes mask. Each block self-detects dtype via bn_v.
// ---------------------------------------------------------------------------
__global__ __launch_bounds__(256) void k_prep(PrepArgs pa,
    const void* __restrict__ bnv, const void* __restrict__ maskp,
    int* __restrict__ flags, int* __restrict__ mbuf,
    float* __restrict__ W, u32* __restrict__ Wb)
{
  const int t = threadIdx.x, bid = blockIdx.x;
  __shared__ int s_nb, s_m4, s_m2;
  if (t == 0) { s_nb = 0; s_m4 = 0; s_m2 = 0; }
  __syncthreads();
  if (t < 64) {
    const u32 w = ((const u32*)bnv)[t];
    if (((w >> 8) & 0xFFu) != 0x3Fu || ((w >> 24) & 0xFFu) != 0x3Fu)
      atomicOr(&s_nb, 1);
  }
  __syncthreads();
  const int isb = s_nb ? 0 : 1;

  if (bid < 16) {
    for (int ten = 0; ten < 19; ++ten) {
      const NEnt E = pa.nrm[ten];
      for (int e = bid * 256 + t; e < E.n; e += 16 * 256)
        W[E.off + e] = rdsrc(E.s, e, isb);
    }
  } else if (bid < 511) {
    for (int g = (bid - 16) * 256 + t; g < PTOT; g += 495 * 256) {
      int ei = 0;
      #pragma unroll
      for (int k = 1; k < 21; ++k) if (g >= pa.pk[k].cum) ei = k;
      const PEnt E = pa.pk[ei];
      const int li = g - E.cum;
      const int e8 = li >> E.lgn, c = li & ((1 << E.lgn) - 1);
      float f[8];
      #pragma unroll
      for (int i = 0; i < 8; ++i) {
        const int si = ((e8 * 8 + i) << E.lgn) + c;
        f[i] = rdsrc(E.s1, E.o1 + si, isb);
        if (E.s2) f[i] += rdsrc(E.s2, E.o2 + si, isb);
      }
      uint4 w;
      w.x = pk2(f[0], f[1]); w.y = pk2(f[2], f[3]);
      w.z = pk2(f[4], f[5]); w.w = pk2(f[6], f[7]);
      ((uint4*)(Wb + E.dst))[li] = w;
    }
  } else {
    {
      const u32 w = ((const u32*)maskp)[t];
      if (!(w == 0u || w == 1u || w == 0x3F800000u)) atomicOr(&s_m4, 1);
      if (!(w == 0u || w == 1u || w == 0x10000u || w == 0x10001u ||
            w == 0x3F80u || w == 0x3F800000u || w == 0x3F803F80u)) atomicOr(&s_m2, 1);
    }
    __syncthreads();
    const int mode = (!s_m4) ? 4 : ((!s_m2) ? 2 : 1);
    if (t == 0) { flags[0] = isb; flags[1] = mode; }
    #pragma unroll
    for (int k = 0; k < 4; ++k) {
      const int e = k * 256 + t;
      int v;
      if (mode == 4)      v = (((const u32*)maskp)[e] != 0u);
      else if (mode == 2) v = (((const u16*)maskp)[e] != 0);
      else                v = (((const u8*)maskp)[e]  != 0);
      mbuf[e] = v;
    }
  }
}

// ---------------------------------------------------------------------------
// k_relq: collapsed pairwise chain + out-MLP + PE + QKV(layer 0).
// 4 rows/block, 256 blocks, 512 threads; GEMM phases on MFMA. (round-8 code)
// ---------------------------------------------------------------------------
__global__ __launch_bounds__(512) void k_relq(
    const void* __restrict__ relv, const float* __restrict__ W,
    const u32* __restrict__ Wb,
    const int* __restrict__ flags, const int* __restrict__ mbuf,
    const int* __restrict__ agent_id, float* __restrict__ xbuf,
    float* __restrict__ qb, u32* __restrict__ kbT, u32* __restrict__ vbT)
{
  const int t = threadIdx.x;            // 0..511
  const int row0 = blockIdx.x * 4;
  const int b = row0 >> 9;
  const int wid = t >> 6;
  const int lane = t & 63;

  __shared__ float pl[4][D], zl[4][D], rl[4][D], os[4][D];
  __shared__ float pA[4][D], pB[4][D];
  __shared__ uint4 aPk[1024];
  __shared__ float wred[8][9];
  __shared__ float sT0[4], sT1[4], sMt;

  // --- P1: masked sums over j of rel channels; Mtot (+ aPk zero-init) ---
  float s0[4] = {0, 0, 0, 0}, s1[4] = {0, 0, 0, 0}, cnt;
  {
    const int j = t;
    const float m = (float)mbuf[b * N + j];
    cnt = m;
    if (flags[0]) {
      const u32* rel2 = (const u32*)relv;
      #pragma unroll
      for (int r = 0; r < 4; ++r) {
        const u32 u = rel2[(size_t)(row0 + r) * N + j];
        s0[r] += m * bf2f((u16)(u & 0xFFFFu));
        s1[r] += m * bf2f((u16)(u >> 16));
      }
    } else {
      const float2* relf = (const float2*)relv;
      #pragma unroll
      for (int r = 0; r < 4; ++r) {
        const float2 u = relf[(size_t)(row0 + r) * N + j];
        s0[r] += m * u.x; s1[r] += m * u.y;
      }
    }
  }
  {
    const uint4 z = {0u, 0u, 0u, 0u};
    aPk[t] = z; aPk[t + 512] = z;
  }
  #pragma unroll
  for (int o = 32; o > 0; o >>= 1) {
    #pragma unroll
    for (int r = 0; r < 4; ++r) {
      s0[r] += __shfl_xor(s0[r], o, 64);
      s1[r] += __shfl_xor(s1[r], o, 64);
    }
    cnt += __shfl_xor(cnt, o, 64);
  }
  if ((t & 63) == 0) {
    #pragma unroll
    for (int r = 0; r < 4; ++r) { wred[wid][r] = s0[r]; wred[wid][4 + r] = s1[r]; }
    wred[wid][8] = cnt;
  }
  __syncthreads();
  if (t < 4) {
    float a0 = 0, a1 = 0;
    #pragma unroll
    for (int w = 0; w < 8; ++w) { a0 += wred[w][t]; a1 += wred[w][4 + t]; }
    sT0[t] = a0; sT1[t] = a1;
  }
  if (t == 8) {
    float c = 0;
    #pragma unroll
    for (int w = 0; w < 8; ++w) c += wred[w][8];
    sMt = c;
  }
  __syncthreads();

  // --- P2: pooled ---
  {
    const int r = t >> 7, c = t & 127;
    const int mi = mbuf[row0 + r];
    pl[r][c] = mi ? (sT0[r] * W[OFF_PRE_W + c] + sT1[r] * W[OFF_PRE_W + D + c]) / sMt
                    + W[OFF_PRE_B + c]
                  : 0.f;
  }
  __syncthreads();

  // --- P3: pooled @ (P1+P2) ---
  packA(&pl[0][0], D, D, aPk, t, 512);
  __syncthreads();
  {
    const int col = wid * 16 + (lane & 15);
    f32x4 acc = mmaKo<4>(aPk, (const uint4*)(Wb + PB_PROJ), 128, col, lane, 0);
    if (lane < 16) {
      #pragma unroll
      for (int g = 0; g < 4; ++g) pA[g][col] = acc[g];
    }
  }
  __syncthreads();
  {
    const int r = t >> 7, d = t & 127;
    zl[r][d] = mbuf[row0 + r] ? pA[r][d] + W[OFF_PROJ_B + d] : 0.f;
  }
  __syncthreads();

  // --- P4: z @ out_w1; bn; relu ---
  packA(&zl[0][0], D, D, aPk, t, 512);
  __syncthreads();
  {
    const int col = wid * 16 + (lane & 15);
    f32x4 acc = mmaKo<4>(aPk, (const uint4*)(Wb + PB_OW1), 128, col, lane, 0);
    if (lane < 16) {
      #pragma unroll
      for (int g = 0; g < 4; ++g) pA[g][col] = acc[g];
    }
  }
  __syncthreads();
  {
    const int r = t >> 7, d = t & 127;
    const float hb = (pA[r][d] - W[OFF_BN_M + d]) * __frsqrt_rn(W[OFF_BN_V + d] + EPS)
                     * W[OFF_BN_G + d] + W[OFF_BN_B + d];
    rl[r][d] = fmaxf(hb, 0.f);
  }
  __syncthreads();

  // --- P5: relu_h @ out_w2 + out_b2 + pe ---
  packA(&rl[0][0], D, D, aPk, t, 512);
  __syncthreads();
  {
    const int col = wid * 16 + (lane & 15);
    f32x4 acc = mmaKo<4>(aPk, (const uint4*)(Wb + PB_OW2), 128, col, lane, 0);
    if (lane < 16) {
      #pragma unroll
      for (int g = 0; g < 4; ++g) pA[g][col] = acc[g];
    }
  }
  __syncthreads();
  {
    const int r = t >> 7, d = t & 127;
    const int aid = agent_id[row0 + r];
    const float x0 = pA[r][d] + W[OFF_OUT_B2 + d] + W[OFF_PE + aid * D + d];
    os[r][d] = x0;
    xbuf[(size_t)(row0 + r) * D + d] = x0;
  }
  __syncthreads();

  // --- P6: QKV layer 0 ---
  packA(&os[0][0], D, D, aPk, t, 512);
  __syncthreads();
  {
    const int col = wid * 16 + (lane & 15);
    #pragma unroll
    for (int m = 0; m < 3; ++m) {
      f32x4 acc = mmaKo<4>(aPk, (const uint4*)(Wb + PB_L0 + m * 8192), 128, col, lane, 0);
      if (lane < 16) {
        const float bb = W[(m == 0 ? OFF_BQ : m == 1 ? OFF_BK : OFF_BV) + col];
        if (m == 0) {
          #pragma unroll
          for (int g = 0; g < 4; ++g) qb[(size_t)(row0 + g) * D + col] = acc[g] + bb;
        } else if (m == 1) {
          #pragma unroll
          for (int g = 0; g < 4; ++g) pA[g][col] = acc[g] + bb;
        } else {
          #pragma unroll
          for (int g = 0; g < 4; ++g) pB[g][col] = acc[g] + bb;
        }
      }
    }
  }
  __syncthreads();
  if (t < 64) {   // packed K^T write: [b][e8][j] uint4
    const int r = t >> 4, e8 = t & 15;
    const float* ks = pA[r];
    uint4 w;
    w.x = pk2(ks[8 * e8 + 0], ks[8 * e8 + 1]);
    w.y = pk2(ks[8 * e8 + 2], ks[8 * e8 + 3]);
    w.z = pk2(ks[8 * e8 + 4], ks[8 * e8 + 5]);
    w.w = pk2(ks[8 * e8 + 6], ks[8 * e8 + 7]);
    ((uint4*)kbT)[((size_t)b * 16 + e8) * 512 + (row0 & 511) + r] = w;
  }
  if (t < 128) {  // packed V write: [b][j8][d] uint4 (half per block)
    const int i0 = row0 & 511, j8 = i0 >> 3, h = (i0 >> 2) & 1;
    uint2 w;
    w.x = pk2(pB[0][t], pB[1][t]);
    w.y = pk2(pB[2][t], pB[3][t]);
    *(uint2*)(vbT + (((size_t)b * 64 + j8) * 128 + t) * 4 + 2 * h) = w;
  }
}

// ---------------------------------------------------------------------------
// k_layer: fused attn + LN1 + FFN + LN2 [+ QKV(l+1)] for 4 rows/block.
// 256 blocks, 1024 threads (16 waves): 512-col phases use all 16 waves;
// K=512/K=128 128-col phases split K across wave halves (partials in pA/pB,
// fp32-combined in the following epilogue). Same math as round 8 otherwise.
// ---------------------------------------------------------------------------
__global__ __launch_bounds__(1024) void k_layer(
    const float* __restrict__ qin, const u32* __restrict__ kinT, const u32* __restrict__ vinT,
    const float* __restrict__ W, const u32* __restrict__ Wb, const int l, const int last,
    float* __restrict__ qout, u32* __restrict__ koutT, u32* __restrict__ voutT,
    const int* __restrict__ mbuf, float* __restrict__ xbuf, float* __restrict__ outp)
{
  const int t = threadIdx.x;            // 0..1023
  const int row0 = blockIdx.x * 4;
  const int b = row0 >> 9;
  const int wid = t >> 6;               // 0..15
  const int lane = t & 63;
  const int w8 = wid & 7, half = wid >> 3;

  const uint4* WOp = (const uint4*)(Wb + PB_L0 + l * PB_LSTR + PB_WO);
  const uint4* W1p = (const uint4*)(Wb + PB_L0 + l * PB_LSTR + PB_FW1);
  const uint4* W2p = (const uint4*)(Wb + PB_L0 + l * PB_LSTR + PB_FW2);
  const float* bo  = W + OFF_BO  + l * D;
  const float* g1  = W + OFF_LN1G + l * D;
  const float* b1  = W + OFF_LN1B + l * D;
  const float* fb1 = W + OFF_FB1 + l * F;
  const float* fb2 = W + OFF_FB2 + l * D;
  const float* g2  = W + OFF_LN2G + l * D;
  const float* b2v = W + OFF_LN2B + l * D;

  __shared__ float qs[4][D];
  __shared__ float bufA[4][512];        // p / hs
  __shared__ float os[4][D];
  __shared__ float xs[4][D];
  __shared__ float pA[4][D], pB[4][D];  // K-split partials / J staging
  __shared__ uint4 aPk[1024];
  __shared__ float den[4];

  // A: load Q rows pre-scaled + zero aPk
  if (t < 512) {
    const int r = t >> 7, d = t & 127;
    qs[r][d] = qin[(size_t)(row0 + r) * D + d] * SCALE;
  }
  {
    const uint4 z = {0u, 0u, 0u, 0u};
    aPk[t & 1023] = z;
  }
  __syncthreads();

  // B: scores via MFMA — 32 col-tasks over 16 waves
  packA(&qs[0][0], D, D, aPk, t, 1024);
  __syncthreads();
  {
    const uint4* Kp = (const uint4*)kinT + (size_t)b * 16 * 512;
    #pragma unroll
    for (int ii = 0; ii < 2; ++ii) {
      const int col = (wid + 16 * ii) * 16 + (lane & 15);
      f32x4 acc = mmaKo<4>(aPk, Kp, 512, col, lane, 0);
      if (lane < 16) {
        const float bias = mbuf[b * N + col] ? 0.f : NEG;
        #pragma unroll
        for (int g = 0; g < 4; ++g) bufA[g][col] = acc[g] + bias;
      }
    }
  }
  __syncthreads();

  // C: softmax — wave w (w<4) handles row w
  if (wid < 4) {
    const int r = wid;
    float pv[8];
    float mx = -1e30f;
    #pragma unroll
    for (int k = 0; k < 8; ++k) { pv[k] = bufA[r][lane + 64 * k]; mx = fmaxf(mx, pv[k]); }
    #pragma unroll
    for (int o = 32; o > 0; o >>= 1) mx = fmaxf(mx, __shfl_xor(mx, o, 64));
    float sum = 0.f;
    #pragma unroll
    for (int k = 0; k < 8; ++k) { pv[k] = __expf(pv[k] - mx); sum += pv[k]; }
    #pragma unroll
    for (int o = 32; o > 0; o >>= 1) sum += __shfl_xor(sum, o, 64);
    #pragma unroll
    for (int k = 0; k < 8; ++k) bufA[r][lane + 64 * k] = pv[k];
    if (lane == 0) den[r] = sum;
  }
  __syncthreads();

  // D: AV via MFMA (K=512 split across wave halves)
  packA(&bufA[0][0], N, N, aPk, t, 1024);
  __syncthreads();
  {
    const int col = w8 * 16 + (lane & 15);
    const uint4* Vp = (const uint4*)vinT + (size_t)b * 64 * 128;
    f32x4 acc = mmaKo<8>(aPk, Vp, 128, col, lane, half * 8);
    if (lane < 16) {
      float* dst = half ? &pB[0][0] : &pA[0][0];
      #pragma unroll
      for (int g = 0; g < 4; ++g) dst[g * D + col] = acc[g];
    }
  }
  __syncthreads();
  if (t < 512) {
    const int r = t >> 7, d = t & 127;
    os[r][d] = (pA[r][d] + pB[r][d]) / den[r];
  }
  __syncthreads();

  // E: WO via MFMA (K=128 split across halves)
  packA(&os[0][0], D, D, aPk, t, 1024);
  __syncthreads();
  {
    const int col = w8 * 16 + (lane & 15);
    f32x4 acc = mmaKo<2>(aPk, WOp, 128, col, lane, half * 2);
    if (lane < 16) {
      float* dst = half ? &pB[0][0] : &pA[0][0];
      #pragma unroll
      for (int g = 0; g < 4; ++g) dst[g * D + col] = acc[g];
    }
  }
  __syncthreads();

  // F: residual + LN1 — wave w handles row w
  if (wid < 4) {
    const int r = wid;
    float tv[2];
    #pragma unroll
    for (int k = 0; k < 2; ++k) {
      const int d = lane + 64 * k;
      tv[k] = pA[r][d] + pB[r][d] + bo[d] + xbuf[(size_t)(row0 + r) * D + d];
    }
    float s = tv[0] + tv[1], sq = tv[0] * tv[0] + tv[1] * tv[1];
    #pragma unroll
    for (int o = 32; o > 0; o >>= 1) { s += __shfl_xor(s, o, 64); sq += __shfl_xor(sq, o, 64); }
    const float mean = s * (1.f / 128.f);
    const float var  = sq * (1.f / 128.f) - mean * mean;
    const float rstd = __frsqrt_rn(var + EPS);
    #pragma unroll
    for (int k = 0; k < 2; ++k) {
      const int d = lane + 64 * k;
      xs[r][d] = (tv[k] - mean) * rstd * g1[d] + b1[d];
    }
  }
  __syncthreads();

  // G: FFN1 via MFMA — 32 col-tasks over 16 waves
  packA(&xs[0][0], D, D, aPk, t, 1024);
  __syncthreads();
  {
    #pragma unroll
    for (int ii = 0; ii < 2; ++ii) {
      const int col = (wid + 16 * ii) * 16 + (lane & 15);
      f32x4 acc = mmaKo<4>(aPk, W1p, 512, col, lane, 0);
      if (lane < 16) {
        const float bb = fb1[col];
        #pragma unroll
        for (int g = 0; g < 4; ++g) bufA[g][col] = fmaxf(acc[g] + bb, 0.f);
      }
    }
  }
  __syncthreads();

  // H: FFN2 via MFMA (K=512 split across halves)
  packA(&bufA[0][0], F, F, aPk, t, 1024);
  __syncthreads();
  {
    const int col = w8 * 16 + (lane & 15);
    f32x4 acc = mmaKo<8>(aPk, W2p, 128, col, lane, half * 8);
    if (lane < 16) {
      float* dst = half ? &pB[0][0] : &pA[0][0];
      #pragma unroll
      for (int g = 0; g < 4; ++g) dst[g * D + col] = acc[g];
    }
  }
  __syncthreads();

  // I: residual + LN2 — wave w handles row w; writes os/xbuf (+outp)
  if (wid < 4) {
    const int r = wid;
    float tv[2];
    #pragma unroll
    for (int k = 0; k < 2; ++k) {
      const int d = lane + 64 * k;
      tv[k] = pA[r][d] + pB[r][d] + fb2[d] + xs[r][d];
    }
    float s = tv[0] + tv[1], sq = tv[0] * tv[0] + tv[1] * tv[1];
    #pragma unroll
    for (int o = 32; o > 0; o >>= 1) { s += __shfl_xor(s, o, 64); sq += __shfl_xor(sq, o, 64); }
    const float mean = s * (1.f / 128.f);
    const float var  = sq * (1.f / 128.f) - mean * mean;
    const float rstd = __frsqrt_rn(var + EPS);
    #pragma unroll
    for (int k = 0; k < 2; ++k) {
      const int d = lane + 64 * k;
      const float xn = (tv[k] - mean) * rstd * g2[d] + b2v[d];
      os[r][d] = xn;
      xbuf[(size_t)(row0 + r) * D + d] = xn;
      if (last) outp[(size_t)(row0 + r) * D + d] = xn;
    }
  }
  __syncthreads();

  // J: QKV for next layer — 24 tasks (m=task>>3) over 16 waves
  if (!last) {
    packA(&os[0][0], D, D, aPk, t, 1024);
    __syncthreads();
    #pragma unroll
    for (int it = 0; it < 2; ++it) {
      const int task = wid + 16 * it;
      if (task < 24) {
        const int m = task >> 3, c8 = task & 7;
        const int col = c8 * 16 + (lane & 15);
        const uint4* Bp = (const uint4*)(Wb + PB_L0 + (l + 1) * PB_LSTR + m * 8192);
        f32x4 acc = mmaKo<4>(aPk, Bp, 128, col, lane, 0);
        if (lane < 16) {
          const float bb = W[(m == 0 ? OFF_BQ : m == 1 ? OFF_BK : OFF_BV) + (l + 1) * D + col];
          if (m == 0) {
            #pragma unroll
            for (int g = 0; g < 4; ++g) qout[(size_t)(row0 + g) * D + col] = acc[g] + bb;
          } else if (m == 1) {
            #pragma unroll
            for (int g = 0; g < 4; ++g) pA[g][col] = acc[g] + bb;
          } else {
            #pragma unroll
            for (int g = 0; g < 4; ++g) pB[g][col] = acc[g] + bb;
          }
        }
      }
    }
    __syncthreads();
    if (t < 64) {
      const int r = t >> 4, e8 = t & 15;
      const float* ks = pA[r];
      uint4 w;
      w.x = pk2(ks[8 * e8 + 0], ks[8 * e8 + 1]);
      w.y = pk2(ks[8 * e8 + 2], ks[8 * e8 + 3]);
      w.z = pk2(ks[8 * e8 + 4], ks[8 * e8 + 5]);
      w.w = pk2(ks[8 * e8 + 6], ks[8 * e8 + 7]);
      ((uint4*)koutT)[((size_t)b * 16 + e8) * 512 + (row0 & 511) + r] = w;
    }
    if (t < 128) {
      const int i0 = row0 & 511, j8 = i0 >> 3, h = (i0 >> 2) & 1;
      uint2 w;
      w.x = pk2(pB[0][t], pB[1][t]);
      w.y = pk2(pB[2][t], pB[3][t]);
      *(uint2*)(voutT + (((size_t)b * 64 + j8) * 128 + t) * 4 + 2 * h) = w;
    }
  }
}

// ---------------------------------------------------------------------------
extern "C" void kernel_launch(void* const* d_in, const int* in_sizes, int n_in,
                              void* d_out, int out_size, void* d_ws, size_t ws_size,
                              hipStream_t stream) {
  // ws layout (4-byte units)
  int*   flags = (int*)d_ws;
  int*   mbuf  = flags + 16;
  float* xbuf  = (float*)d_ws + 1040;
  float* q0    = xbuf + NROW * D;
  float* q1    = q0 + NROW * D;
  u32*   kT0   = (u32*)(q1 + NROW * D);      // [B][16][512] uint4
  u32*   kT1   = kT0 + 65536;
  u32*   vT0   = kT1 + 65536;                // [B][64][128] uint4
  u32*   vT1   = vT0 + 65536;
  float* W     = (float*)(vT1 + 65536);
  u32*   Wb    = (u32*)(W + W_TOTAL);

  PrepArgs pa;
  {
    const NEnt nrm[19] = {
      {d_in[1],  OFF_PRE_W,  256}, {d_in[2],  OFF_PRE_B, 128},
      {d_in[4],  OFF_PROJ_B, 128},
      {d_in[6],  OFF_BN_G,   128}, {d_in[7],  OFF_BN_B,  128},
      {d_in[8],  OFF_BN_M,   128}, {d_in[9],  OFF_BN_V,  128},
      {d_in[11], OFF_OUT_B2, 128}, {d_in[12], OFF_PE,  16384},
      {d_in[14], OFF_BQ,     384}, {d_in[16], OFF_BK,    384},
      {d_in[18], OFF_BV,     384}, {d_in[20], OFF_BO,    384},
      {d_in[21], OFF_LN1G,   384}, {d_in[22], OFF_LN1B,  384},
      {d_in[23], OFF_LN2G,   384}, {d_in[24], OFF_LN2B,  384},
      {d_in[26], OFF_FB1,   1536}, {d_in[28], OFF_FB2,   384}};
    for (int i = 0; i < 19; ++i) pa.nrm[i] = nrm[i];

    pa.pk[0] = {d_in[3], d_in[3], 0, 16384, PB_PROJ, 7, 0};
    pa.pk[1] = {d_in[5],  nullptr, 0, 0, PB_OW1, 7, 2048};
    pa.pk[2] = {d_in[10], nullptr, 0, 0, PB_OW2, 7, 4096};
    for (int l = 0; l < 3; ++l) {
      const int lb = PB_L0 + l * PB_LSTR;
      const int cl = 6144 + l * 24576;
      pa.pk[3 + 6 * l + 0] = {d_in[13], nullptr, l * 16384, 0, lb,          7, cl};
      pa.pk[3 + 6 * l + 1] = {d_in[15], nullptr, l * 16384, 0, lb + 8192,   7, cl + 2048};
      pa.pk[3 + 6 * l + 2] = {d_in[17], nullptr, l * 16384, 0, lb + 16384,  7, cl + 4096};
      pa.pk[3 + 6 * l + 3] = {d_in[19], nullptr, l * 16384, 0, lb + PB_WO,  7, cl + 6144};
      pa.pk[3 + 6 * l + 4] = {d_in[25], nullptr, l * 65536, 0, lb + PB_FW1, 9, cl + 8192};
      pa.pk[3 + 6 * l + 5] = {d_in[27], nullptr, l * 65536, 0, lb + PB_FW2, 7, cl + 16384};
    }
  }
  const int* agent_id = (const int*)d_in[30];

  k_prep<<<512, 256, 0, stream>>>(pa, d_in[9], d_in[29], flags, mbuf, W, Wb);
  k_relq<<<NROW / 4, 512, 0, stream>>>(d_in[0], W, Wb, flags, mbuf, agent_id, xbuf,
                                       q0, kT0, vT0);

  float* qs_[2] = {q0, q1};
  u32*   ks_[2] = {kT0, kT1};
  u32*   vs_[2] = {vT0, vT1};
  for (int l = 0; l < 3; ++l) {
    const int cur = l & 1, nxt = cur ^ 1;
    const int last = (l == 2);
    k_layer<<<NROW / 4, 1024, 0, stream>>>(
        qs_[cur], ks_[cur], vs_[cur],
        W, Wb, l, last,
        qs_[nxt], ks_[nxt], vs_[nxt],
        mbuf, xbuf, last ? (float*)d_out : (float*)nullptr);
  }
}

// Round 12
// 66.635 us; speedup vs baseline: 2.8297x; 1.0174x over previous
//
#include <hip/hip_runtime.h>
#include <hip/hip_bf16.h>

typedef unsigned short u16;
typedef unsigned int u32;
typedef unsigned char u8;
typedef __attribute__((ext_vector_type(8))) short bf16x8;
typedef __attribute__((ext_vector_type(4))) float f32x4;

#define DEV __device__ __forceinline__

DEV float bf2f(u16 u) { union { u32 i; float f; } c; c.i = ((u32)u) << 16; return c.f; }
DEV u16 f2bf(float f) {  // round-to-nearest-even
  union { float f; u32 i; } c; c.f = f;
  u32 r = c.i + 0x7FFFu + ((c.i >> 16) & 1u);
  return (u16)(r >> 16);
}
DEV u32 pk2(float lo, float hi) { return (u32)f2bf(lo) | ((u32)f2bf(hi) << 16); }
DEV float rdsrc(const void* p, int e, int isb) {
  return isb ? bf2f(((const u16*)p)[e]) : ((const float*)p)[e];
}
DEV bf16x8 as_bf(uint4 v) { union { uint4 u; bf16x8 h; } c; c.u = v; return c.h; }

static constexpr int B = 2, N = 512, D = 128, F = 512;
static constexpr int NROW = B * N;  // 1024
static constexpr float EPS = 1e-5f;
static constexpr float NEG = -1e9f;
static constexpr float SCALE = 0.08838834764831845f;  // 1/sqrt(128)

// ---- fp32 small-weight region offsets ------------------------------------
#define OFF_PRE_W   0
#define OFF_PRE_B   256
#define OFF_PROJ_B  33152
#define OFF_BN_G    49664
#define OFF_BN_B    49792
#define OFF_BN_M    49920
#define OFF_BN_V    50048
#define OFF_OUT_B2  66560
#define OFF_PE      66688
#define OFF_BQ      132224
#define OFF_BK      181760
#define OFF_BV      231296
#define OFF_BO      280832
#define OFF_LN1G    281216
#define OFF_LN1B    281600
#define OFF_LN2G    281984
#define OFF_LN2B    282368
#define OFF_FB1     479360
#define OFF_FB2     677504
#define W_TOTAL     677888

// ---- packed-bf16 weight region (u32 units; [e8][col] uint4 of 8 K-elems) --
static constexpr int PB_PROJ = 0;
static constexpr int PB_OW1  = 8192;
static constexpr int PB_OW2  = 16384;
static constexpr int PB_L0   = 24576;
static constexpr int PB_LSTR = 98304;
static constexpr int PB_WO   = 24576;
static constexpr int PB_FW1  = 32768;
static constexpr int PB_FW2  = 65536;
static constexpr int PTOT    = 79872;   // total uint4 pack entries

struct NEnt { const void* s; int off, n; };
struct PEnt { const void* s1; const void* s2; int o1, o2, dst, lgn, cum; };
struct PrepArgs { NEnt nrm[19]; PEnt pk[21]; };

// ---------------------------------------------------------------------------
// MFMA helpers (round-8 verified): A rows 0..3 live, rows 4..15 zero, packed
// [e8][16] uint4 in LDS; B = [e8][ncol] uint4. D rows 0..3 -> lanes 0..15,
// regs 0..3. mmaKo: K-offset for wave-half K splits.
// ---------------------------------------------------------------------------
template<int KT>
DEV f32x4 mmaKo(const uint4* __restrict__ aPk, const uint4* __restrict__ Bp,
                int ncol, int col, int lane, int kt0) {
  f32x4 acc = {0.f, 0.f, 0.f, 0.f};
  const int sub = lane >> 4;
  #pragma unroll
  for (int kt = 0; kt < KT; ++kt) {
    const int e8 = (kt0 + kt) * 4 + sub;
    acc = __builtin_amdgcn_mfma_f32_16x16x32_bf16(
        as_bf(aPk[e8 * 16 + (lane & 15)]),
        as_bf(Bp[(size_t)e8 * ncol + col]),
        acc, 0, 0, 0);
  }
  return acc;
}

// Epilogue pack, (r,d) decomposition: thread holds one value for row r, col d.
// Pairs via shfl_xor(1) (d pairs lie within a wave); even-d thread writes u32.
DEV void packRD(u32* aPkU, int r, int d, float v) {
  const float p = __shfl_xor(v, 1, 64);
  if (!(d & 1))
    aPkU[(((d >> 3) * 16 + r) << 2) + ((d >> 1) & 3)] = pk2(v, p);
}

// Epilogue pack, mma-epilogue decomposition: lanes 0..15 hold cols
// colbase+0..15, regs g = rows 0..3. Call with lanes 0..15 active.
DEV void packP16(u32* aPkU, int colbase, int lane, f32x4 v) {
  f32x4 p;
  #pragma unroll
  for (int g = 0; g < 4; ++g) p[g] = __shfl_xor(v[g], 1, 64);
  if (!(lane & 1)) {
    const int c = colbase + lane;
    const int e8 = c >> 3, slot = (c >> 1) & 3;
    #pragma unroll
    for (int g = 0; g < 4; ++g)
      aPkU[((e8 * 16 + g) << 2) + slot] = pk2(v[g], p[g]);
  }
}

// ---------------------------------------------------------------------------
// k_prep (512 blocks): 0..15 norm small tensors; 16..510 build packed
// weights; 511 normalizes mask. Each block self-detects dtype via bn_v.
// ---------------------------------------------------------------------------
__global__ __launch_bounds__(256) void k_prep(PrepArgs pa,
    const void* __restrict__ bnv, const void* __restrict__ maskp,
    int* __restrict__ flags, int* __restrict__ mbuf,
    float* __restrict__ W, u32* __restrict__ Wb)
{
  const int t = threadIdx.x, bid = blockIdx.x;
  __shared__ int s_nb, s_m4, s_m2;
  if (t == 0) { s_nb = 0; s_m4 = 0; s_m2 = 0; }
  __syncthreads();
  if (t < 64) {
    const u32 w = ((const u32*)bnv)[t];
    if (((w >> 8) & 0xFFu) != 0x3Fu || ((w >> 24) & 0xFFu) != 0x3Fu)
      atomicOr(&s_nb, 1);
  }
  __syncthreads();
  const int isb = s_nb ? 0 : 1;

  if (bid < 16) {
    for (int ten = 0; ten < 19; ++ten) {
      const NEnt E = pa.nrm[ten];
      for (int e = bid * 256 + t; e < E.n; e += 16 * 256)
        W[E.off + e] = rdsrc(E.s, e, isb);
    }
  } else if (bid < 511) {
    for (int g = (bid - 16) * 256 + t; g < PTOT; g += 495 * 256) {
      int ei = 0;
      #pragma unroll
      for (int k = 1; k < 21; ++k) if (g >= pa.pk[k].cum) ei = k;
      const PEnt E = pa.pk[ei];
      const int li = g - E.cum;
      const int e8 = li >> E.lgn, c = li & ((1 << E.lgn) - 1);
      float f[8];
      #pragma unroll
      for (int i = 0; i < 8; ++i) {
        const int si = ((e8 * 8 + i) << E.lgn) + c;
        f[i] = rdsrc(E.s1, E.o1 + si, isb);
        if (E.s2) f[i] += rdsrc(E.s2, E.o2 + si, isb);
      }
      uint4 w;
      w.x = pk2(f[0], f[1]); w.y = pk2(f[2], f[3]);
      w.z = pk2(f[4], f[5]); w.w = pk2(f[6], f[7]);
      ((uint4*)(Wb + E.dst))[li] = w;
    }
  } else {
    {
      const u32 w = ((const u32*)maskp)[t];
      if (!(w == 0u || w == 1u || w == 0x3F800000u)) atomicOr(&s_m4, 1);
      if (!(w == 0u || w == 1u || w == 0x10000u || w == 0x10001u ||
            w == 0x3F80u || w == 0x3F800000u || w == 0x3F803F80u)) atomicOr(&s_m2, 1);
    }
    __syncthreads();
    const int mode = (!s_m4) ? 4 : ((!s_m2) ? 2 : 1);
    if (t == 0) { flags[0] = isb; flags[1] = mode; }
    #pragma unroll
    for (int k = 0; k < 4; ++k) {
      const int e = k * 256 + t;
      int v;
      if (mode == 4)      v = (((const u32*)maskp)[e] != 0u);
      else if (mode == 2) v = (((const u16*)maskp)[e] != 0);
      else                v = (((const u8*)maskp)[e]  != 0);
      mbuf[e] = v;
    }
  }
}

// ---------------------------------------------------------------------------
// k_relq: collapsed pairwise chain + out-MLP + PE + QKV(layer 0).
// 4 rows/block, 256 blocks, 512 threads. Pack-in-epilogue, aPk double-buffer.
// ---------------------------------------------------------------------------
__global__ __launch_bounds__(512) void k_relq(
    const void* __restrict__ relv, const float* __restrict__ W,
    const u32* __restrict__ Wb,
    const int* __restrict__ flags, const int* __restrict__ mbuf,
    const int* __restrict__ agent_id, float* __restrict__ xbuf,
    float* __restrict__ qb, u32* __restrict__ kbT, u32* __restrict__ vbT)
{
  const int t = threadIdx.x;            // 0..511
  const int row0 = blockIdx.x * 4;
  const int b = row0 >> 9;
  const int wid = t >> 6;
  const int lane = t & 63;

  __shared__ uint4 aPk[2][256];         // K=128 GEMMs: e8 0..15
  __shared__ float wred[8][9];
  __shared__ float sT0[4], sT1[4], sMt;

  u32* a0 = (u32*)&aPk[0][0];
  u32* a1 = (u32*)&aPk[1][0];

  // --- P1: masked sums over j of rel channels; Mtot; zero aPk rows 4..15 ---
  float s0[4] = {0, 0, 0, 0}, s1[4] = {0, 0, 0, 0}, cnt;
  {
    const int j = t;
    const float m = (float)mbuf[b * N + j];
    cnt = m;
    if (flags[0]) {
      const u32* rel2 = (const u32*)relv;
      #pragma unroll
      for (int r = 0; r < 4; ++r) {
        const u32 u = rel2[(size_t)(row0 + r) * N + j];
        s0[r] += m * bf2f((u16)(u & 0xFFFFu));
        s1[r] += m * bf2f((u16)(u >> 16));
      }
    } else {
      const float2* relf = (const float2*)relv;
      #pragma unroll
      for (int r = 0; r < 4; ++r) {
        const float2 u = relf[(size_t)(row0 + r) * N + j];
        s0[r] += m * u.x; s1[r] += m * u.y;
      }
    }
  }
  if ((t & 15) >= 4) {                  // entries for rows 4..15 (never packed)
    const uint4 z = {0u, 0u, 0u, 0u};
    aPk[t >> 8][t & 255] = z;
  }
  #pragma unroll
  for (int o = 32; o > 0; o >>= 1) {
    #pragma unroll
    for (int r = 0; r < 4; ++r) {
      s0[r] += __shfl_xor(s0[r], o, 64);
      s1[r] += __shfl_xor(s1[r], o, 64);
    }
    cnt += __shfl_xor(cnt, o, 64);
  }
  if ((t & 63) == 0) {
    #pragma unroll
    for (int r = 0; r < 4; ++r) { wred[wid][r] = s0[r]; wred[wid][4 + r] = s1[r]; }
    wred[wid][8] = cnt;
  }
  __syncthreads();
  if (t < 4) {
    float a0v = 0, a1v = 0;
    #pragma unroll
    for (int w = 0; w < 8; ++w) { a0v += wred[w][t]; a1v += wred[w][4 + t]; }
    sT0[t] = a0v; sT1[t] = a1v;
  }
  if (t == 8) {
    float c = 0;
    #pragma unroll
    for (int w = 0; w < 8; ++w) c += wred[w][8];
    sMt = c;
  }
  __syncthreads();

  // --- P2: pooled -> pack a0 ---
  {
    const int r = t >> 7, c = t & 127;
    const int mi = mbuf[row0 + r];
    const float v = mi ? (sT0[r] * W[OFF_PRE_W + c] + sT1[r] * W[OFF_PRE_W + D + c]) / sMt
                         + W[OFF_PRE_B + c]
                       : 0.f;
    packRD(a0, r, c, v);
  }
  __syncthreads();

  // --- P3: pooled @ (P1+P2) -> z (mask, +bias) -> pack a1 ---
  {
    const int col = wid * 16 + (lane & 15);
    f32x4 acc = mmaKo<4>(&aPk[0][0], (const uint4*)(Wb + PB_PROJ), 128, col, lane, 0);
    if (lane < 16) {
      const float pb = W[OFF_PROJ_B + col];
      f32x4 v;
      #pragma unroll
      for (int g = 0; g < 4; ++g) v[g] = mbuf[row0 + g] ? acc[g] + pb : 0.f;
      packP16(a1, wid * 16, lane, v);
    }
  }
  __syncthreads();

  // --- P4: z @ out_w1 -> bn -> relu -> pack a0 ---
  {
    const int col = wid * 16 + (lane & 15);
    f32x4 acc = mmaKo<4>(&aPk[1][0], (const uint4*)(Wb + PB_OW1), 128, col, lane, 0);
    if (lane < 16) {
      const float bnm = W[OFF_BN_M + col];
      const float rs  = __frsqrt_rn(W[OFF_BN_V + col] + EPS);
      const float bg  = W[OFF_BN_G + col], bb = W[OFF_BN_B + col];
      f32x4 v;
      #pragma unroll
      for (int g = 0; g < 4; ++g) v[g] = fmaxf((acc[g] - bnm) * rs * bg + bb, 0.f);
      packP16(a0, wid * 16, lane, v);
    }
  }
  __syncthreads();

  // --- P5: relu_h @ out_w2 + out_b2 + pe -> xbuf + pack a1 ---
  {
    const int col = wid * 16 + (lane & 15);
    f32x4 acc = mmaKo<4>(&aPk[0][0], (const uint4*)(Wb + PB_OW2), 128, col, lane, 0);
    if (lane < 16) {
      const float ob = W[OFF_OUT_B2 + col];
      f32x4 v;
      #pragma unroll
      for (int g = 0; g < 4; ++g) {
        const int aid = agent_id[row0 + g];
        v[g] = acc[g] + ob + W[OFF_PE + aid * D + col];
        xbuf[(size_t)(row0 + g) * D + col] = v[g];
      }
      packP16(a1, wid * 16, lane, v);
    }
  }
  __syncthreads();

  // --- P6: QKV layer 0 (from a1) — Q/K/V straight to global ---
  {
    const int col = wid * 16 + (lane & 15);
    const int i0 = row0 & 511;
    #pragma unroll
    for (int m = 0; m < 3; ++m) {
      f32x4 acc = mmaKo<4>(&aPk[1][0], (const uint4*)(Wb + PB_L0 + m * 8192), 128, col, lane, 0);
      if (lane < 16) {
        const float bb = W[(m == 0 ? OFF_BQ : m == 1 ? OFF_BK : OFF_BV) + col];
        f32x4 v;
        #pragma unroll
        for (int g = 0; g < 4; ++g) v[g] = acc[g] + bb;
        if (m == 0) {
          #pragma unroll
          for (int g = 0; g < 4; ++g) qb[(size_t)(row0 + g) * D + col] = v[g];
        } else if (m == 1) {
          f32x4 p;
          #pragma unroll
          for (int g = 0; g < 4; ++g) p[g] = __shfl_xor(v[g], 1, 64);
          if (!(lane & 1)) {
            const int e8 = col >> 3, slot = (col >> 1) & 3;
            #pragma unroll
            for (int g = 0; g < 4; ++g)
              ((u32*)kbT)[(((size_t)b * 16 + e8) * 512 + i0 + g) * 4 + slot] = pk2(v[g], p[g]);
          }
        } else {
          uint2 w;
          w.x = pk2(v[0], v[1]); w.y = pk2(v[2], v[3]);
          *(uint2*)(vbT + (((size_t)b * 64 + (i0 >> 3)) * 128 + col) * 4 + 2 * ((i0 >> 2) & 1)) = w;
        }
      }
    }
  }
}

// ---------------------------------------------------------------------------
// k_layer: fused attn + LN1 + FFN + LN2 [+ QKV(l+1)] for 4 rows/block.
// 256 blocks, 1024 threads. Pack-in-epilogue; aPk double-buffer
// (q->a0, p->a1, os->a0, xs->a1, hs->a0, xn->a1).
// ---------------------------------------------------------------------------
__global__ __launch_bounds__(1024) void k_layer(
    const float* __restrict__ qin, const u32* __restrict__ kinT, const u32* __restrict__ vinT,
    const float* __restrict__ W, const u32* __restrict__ Wb, const int l, const int last,
    float* __restrict__ qout, u32* __restrict__ koutT, u32* __restrict__ voutT,
    const int* __restrict__ mbuf, float* __restrict__ xbuf, float* __restrict__ outp)
{
  const int t = threadIdx.x;            // 0..1023
  const int row0 = blockIdx.x * 4;
  const int b = row0 >> 9;
  const int wid = t >> 6;               // 0..15
  const int lane = t & 63;
  const int w8 = wid & 7, half = wid >> 3;

  const uint4* WOp = (const uint4*)(Wb + PB_L0 + l * PB_LSTR + PB_WO);
  const uint4* W1p = (const uint4*)(Wb + PB_L0 + l * PB_LSTR + PB_FW1);
  const uint4* W2p = (const uint4*)(Wb + PB_L0 + l * PB_LSTR + PB_FW2);
  const float* bo  = W + OFF_BO  + l * D;
  const float* g1  = W + OFF_LN1G + l * D;
  const float* b1  = W + OFF_LN1B + l * D;
  const float* fb1 = W + OFF_FB1 + l * F;
  const float* fb2 = W + OFF_FB2 + l * D;
  const float* g2  = W + OFF_LN2G + l * D;
  const float* b2v = W + OFF_LN2B + l * D;

  __shared__ float bufA[4][512];        // scores
  __shared__ float xs[4][D];
  __shared__ float pA[4][D], pB[4][D];  // K-split partials
  __shared__ uint4 aPk[2][1024];
  __shared__ float den[4];

  u32* a0 = (u32*)&aPk[0][0];
  u32* a1 = (u32*)&aPk[1][0];

  // Phase A: zero rows 4..15 of both aPk buffers + Q load/scale/pack -> a0
  for (int i = t; i < 2048; i += 1024)
    if ((i & 15) >= 4) {
      const uint4 z = {0u, 0u, 0u, 0u};
      aPk[i >> 10][i & 1023] = z;
    }
  if (t < 512) {
    const int r = t >> 7, d = t & 127;
    packRD(a0, r, d, qin[(size_t)(row0 + r) * D + d] * SCALE);
  }
  __syncthreads();

  // B: scores via MFMA (a0) — bias epilogue -> bufA
  {
    const uint4* Kp = (const uint4*)kinT + (size_t)b * 16 * 512;
    #pragma unroll
    for (int ii = 0; ii < 2; ++ii) {
      const int col = (wid + 16 * ii) * 16 + (lane & 15);
      f32x4 acc = mmaKo<4>(&aPk[0][0], Kp, 512, col, lane, 0);
      if (lane < 16) {
        const float bias = mbuf[b * N + col] ? 0.f : NEG;
        #pragma unroll
        for (int g = 0; g < 4; ++g) bufA[g][col] = acc[g] + bias;
      }
    }
  }
  __syncthreads();

  // C: softmax (wave r<4) — packs exp -> a1
  if (wid < 4) {
    const int r = wid;
    float pv[8];
    float mx = -1e30f;
    #pragma unroll
    for (int k = 0; k < 8; ++k) { pv[k] = bufA[r][lane + 64 * k]; mx = fmaxf(mx, pv[k]); }
    #pragma unroll
    for (int o = 32; o > 0; o >>= 1) mx = fmaxf(mx, __shfl_xor(mx, o, 64));
    float sum = 0.f;
    #pragma unroll
    for (int k = 0; k < 8; ++k) { pv[k] = __expf(pv[k] - mx); sum += pv[k]; }
    #pragma unroll
    for (int o = 32; o > 0; o >>= 1) sum += __shfl_xor(sum, o, 64);
    #pragma unroll
    for (int k = 0; k < 8; ++k) {
      const float pp = __shfl_xor(pv[k], 1, 64);
      if (!(lane & 1)) {
        const int c = lane + 64 * k;
        a1[(((c >> 3) * 16 + r) << 2) + ((c >> 1) & 3)] = pk2(pv[k], pp);
      }
    }
    if (lane == 0) den[r] = sum;
  }
  __syncthreads();

  // D: AV via MFMA (a1, K=512 split) -> partials pA/pB
  {
    const int col = w8 * 16 + (lane & 15);
    const uint4* Vp = (const uint4*)vinT + (size_t)b * 64 * 128;
    f32x4 acc = mmaKo<8>(&aPk[1][0], Vp, 128, col, lane, half * 8);
    if (lane < 16) {
      float* dst = half ? &pB[0][0] : &pA[0][0];
      #pragma unroll
      for (int g = 0; g < 4; ++g) dst[g * D + col] = acc[g];
    }
  }
  __syncthreads();

  // D-combine: os = (pA+pB)/den -> pack a0
  if (t < 512) {
    const int r = t >> 7, d = t & 127;
    packRD(a0, r, d, (pA[r][d] + pB[r][d]) / den[r]);
  }
  __syncthreads();

  // E: WO via MFMA (a0, K=128 split) -> partials pA/pB
  {
    const int col = w8 * 16 + (lane & 15);
    f32x4 acc = mmaKo<2>(&aPk[0][0], WOp, 128, col, lane, half * 2);
    if (lane < 16) {
      float* dst = half ? &pB[0][0] : &pA[0][0];
      #pragma unroll
      for (int g = 0; g < 4; ++g) dst[g * D + col] = acc[g];
    }
  }
  __syncthreads();

  // F: residual + LN1 (wave r<4) — xs write + pack a1
  if (wid < 4) {
    const int r = wid;
    float tv[2];
    #pragma unroll
    for (int k = 0; k < 2; ++k) {
      const int d = lane + 64 * k;
      tv[k] = pA[r][d] + pB[r][d] + bo[d] + xbuf[(size_t)(row0 + r) * D + d];
    }
    float s = tv[0] + tv[1], sq = tv[0] * tv[0] + tv[1] * tv[1];
    #pragma unroll
    for (int o = 32; o > 0; o >>= 1) { s += __shfl_xor(s, o, 64); sq += __shfl_xor(sq, o, 64); }
    const float mean = s * (1.f / 128.f);
    const float var  = sq * (1.f / 128.f) - mean * mean;
    const float rstd = __frsqrt_rn(var + EPS);
    #pragma unroll
    for (int k = 0; k < 2; ++k) {
      const int d = lane + 64 * k;
      const float xn = (tv[k] - mean) * rstd * g1[d] + b1[d];
      xs[r][d] = xn;
      const float pp = __shfl_xor(xn, 1, 64);
      if (!(lane & 1))
        a1[(((d >> 3) * 16 + r) << 2) + ((d >> 1) & 3)] = pk2(xn, pp);
    }
  }
  __syncthreads();

  // G: FFN1 via MFMA (a1) — relu epilogue packs -> a0
  {
    #pragma unroll
    for (int ii = 0; ii < 2; ++ii) {
      const int colbase = (wid + 16 * ii) * 16;
      const int col = colbase + (lane & 15);
      f32x4 acc = mmaKo<4>(&aPk[1][0], W1p, 512, col, lane, 0);
      if (lane < 16) {
        const float bb = fb1[col];
        f32x4 v;
        #pragma unroll
        for (int g = 0; g < 4; ++g) v[g] = fmaxf(acc[g] + bb, 0.f);
        packP16(a0, colbase, lane, v);
      }
    }
  }
  __syncthreads();

  // H: FFN2 via MFMA (a0, K=512 split) -> partials pA/pB
  {
    const int col = w8 * 16 + (lane & 15);
    f32x4 acc = mmaKo<8>(&aPk[0][0], W2p, 128, col, lane, half * 8);
    if (lane < 16) {
      float* dst = half ? &pB[0][0] : &pA[0][0];
      #pragma unroll
      for (int g = 0; g < 4; ++g) dst[g * D + col] = acc[g];
    }
  }
  __syncthreads();

  // I: residual + LN2 (wave r<4) — xbuf/outp write + pack a1 (if !last)
  if (wid < 4) {
    const int r = wid;
    float tv[2];
    #pragma unroll
    for (int k = 0; k < 2; ++k) {
      const int d = lane + 64 * k;
      tv[k] = pA[r][d] + pB[r][d] + fb2[d] + xs[r][d];
    }
    float s = tv[0] + tv[1], sq = tv[0] * tv[0] + tv[1] * tv[1];
    #pragma unroll
    for (int o = 32; o > 0; o >>= 1) { s += __shfl_xor(s, o, 64); sq += __shfl_xor(sq, o, 64); }
    const float mean = s * (1.f / 128.f);
    const float var  = sq * (1.f / 128.f) - mean * mean;
    const float rstd = __frsqrt_rn(var + EPS);
    #pragma unroll
    for (int k = 0; k < 2; ++k) {
      const int d = lane + 64 * k;
      const float xn = (tv[k] - mean) * rstd * g2[d] + b2v[d];
      xbuf[(size_t)(row0 + r) * D + d] = xn;
      if (last) outp[(size_t)(row0 + r) * D + d] = xn;
      const float pp = __shfl_xor(xn, 1, 64);
      if (!last && !(lane & 1))
        a1[(((d >> 3) * 16 + r) << 2) + ((d >> 1) & 3)] = pk2(xn, pp);
    }
  }

  // J: QKV for next layer (from a1) — straight to global
  if (!last) {
    __syncthreads();
    const int i0 = row0 & 511;
    #pragma unroll
    for (int it = 0; it < 2; ++it) {
      const int task = wid + 16 * it;
      if (task < 24) {
        const int m = task >> 3, c8 = task & 7;
        const int col = c8 * 16 + (lane & 15);
        const uint4* Bp = (const uint4*)(Wb + PB_L0 + (l + 1) * PB_LSTR + m * 8192);
        f32x4 acc = mmaKo<4>(&aPk[1][0], Bp, 128, col, lane, 0);
        if (lane < 16) {
          const float bb = W[(m == 0 ? OFF_BQ : m == 1 ? OFF_BK : OFF_BV) + (l + 1) * D + col];
          f32x4 v;
          #pragma unroll
          for (int g = 0; g < 4; ++g) v[g] = acc[g] + bb;
          if (m == 0) {
            #pragma unroll
            for (int g = 0; g < 4; ++g) qout[(size_t)(row0 + g) * D + col] = v[g];
          } else if (m == 1) {
            f32x4 p;
            #pragma unroll
            for (int g = 0; g < 4; ++g) p[g] = __shfl_xor(v[g], 1, 64);
            if (!(lane & 1)) {
              const int e8 = col >> 3, slot = (col >> 1) & 3;
              #pragma unroll
              for (int g = 0; g < 4; ++g)
                ((u32*)koutT)[(((size_t)b * 16 + e8) * 512 + i0 + g) * 4 + slot] = pk2(v[g], p[g]);
            }
          } else {
            uint2 w;
            w.x = pk2(v[0], v[1]); w.y = pk2(v[2], v[3]);
            *(uint2*)(voutT + (((size_t)b * 64 + (i0 >> 3)) * 128 + col) * 4 + 2 * ((i0 >> 2) & 1)) = w;
          }
        }
      }
    }
  }
}

// ---------------------------------------------------------------------------
extern "C" void kernel_launch(void* const* d_in, const int* in_sizes, int n_in,
                              void* d_out, int out_size, void* d_ws, size_t ws_size,
                              hipStream_t stream) {
  // ws layout (4-byte units)
  int*   flags = (int*)d_ws;
  int*   mbuf  = flags + 16;
  float* xbuf  = (float*)d_ws + 1040;
  float* q0    = xbuf + NROW * D;
  float* q1    = q0 + NROW * D;
  u32*   kT0   = (u32*)(q1 + NROW * D);      // [B][16][512] uint4
  u32*   kT1   = kT0 + 65536;
  u32*   vT0   = kT1 + 65536;                // [B][64][128] uint4
  u32*   vT1   = vT0 + 65536;
  float* W     = (float*)(vT1 + 65536);
  u32*   Wb    = (u32*)(W + W_TOTAL);

  PrepArgs pa;
  {
    const NEnt nrm[19] = {
      {d_in[1],  OFF_PRE_W,  256}, {d_in[2],  OFF_PRE_B, 128},
      {d_in[4],  OFF_PROJ_B, 128},
      {d_in[6],  OFF_BN_G,   128}, {d_in[7],  OFF_BN_B,  128},
      {d_in[8],  OFF_BN_M,   128}, {d_in[9],  OFF_BN_V,  128},
      {d_in[11], OFF_OUT_B2, 128}, {d_in[12], OFF_PE,  16384},
      {d_in[14], OFF_BQ,     384}, {d_in[16], OFF_BK,    384},
      {d_in[18], OFF_BV,     384}, {d_in[20], OFF_BO,    384},
      {d_in[21], OFF_LN1G,   384}, {d_in[22], OFF_LN1B,  384},
      {d_in[23], OFF_LN2G,   384}, {d_in[24], OFF_LN2B,  384},
      {d_in[26], OFF_FB1,   1536}, {d_in[28], OFF_FB2,   384}};
    for (int i = 0; i < 19; ++i) pa.nrm[i] = nrm[i];

    pa.pk[0] = {d_in[3], d_in[3], 0, 16384, PB_PROJ, 7, 0};
    pa.pk[1] = {d_in[5],  nullptr, 0, 0, PB_OW1, 7, 2048};
    pa.pk[2] = {d_in[10], nullptr, 0, 0, PB_OW2, 7, 4096};
    for (int l = 0; l < 3; ++l) {
      const int lb = PB_L0 + l * PB_LSTR;
      const int cl = 6144 + l * 24576;
      pa.pk[3 + 6 * l + 0] = {d_in[13], nullptr, l * 16384, 0, lb,          7, cl};
      pa.pk[3 + 6 * l + 1] = {d_in[15], nullptr, l * 16384, 0, lb + 8192,   7, cl + 2048};
      pa.pk[3 + 6 * l + 2] = {d_in[17], nullptr, l * 16384, 0, lb + 16384,  7, cl + 4096};
      pa.pk[3 + 6 * l + 3] = {d_in[19], nullptr, l * 16384, 0, lb + PB_WO,  7, cl + 6144};
      pa.pk[3 + 6 * l + 4] = {d_in[25], nullptr, l * 65536, 0, lb + PB_FW1, 9, cl + 8192};
      pa.pk[3 + 6 * l + 5] = {d_in[27], nullptr, l * 65536, 0, lb + PB_FW2, 7, cl + 16384};
    }
  }
  const int* agent_id = (const int*)d_in[30];

  k_prep<<<512, 256, 0, stream>>>(pa, d_in[9], d_in[29], flags, mbuf, W, Wb);
  k_relq<<<NROW / 4, 512, 0, stream>>>(d_in[0], W, Wb, flags, mbuf, agent_id, xbuf,
                                       q0, kT0, vT0);

  float* qs_[2] = {q0, q1};
  u32*   ks_[2] = {kT0, kT1};
  u32*   vs_[2] = {vT0, vT1};
  for (int l = 0; l < 3; ++l) {
    const int cur = l & 1, nxt = cur ^ 1;
    const int last = (l == 2);
    k_layer<<<NROW / 4, 1024, 0, stream>>>(
        qs_[cur], ks_[cur], vs_[cur],
        W, Wb, l, last,
        qs_[nxt], ks_[nxt], vs_[nxt],
        mbuf, xbuf, last ? (float*)d_out : (float*)nullptr);
  }
}

// Round 13
// 63.110 us; speedup vs baseline: 2.9878x; 1.0559x over previous
//
#include <hip/hip_runtime.h>
#include <hip/hip_bf16.h>

typedef unsigned short u16;
typedef unsigned int u32;
typedef unsigned char u8;
typedef __attribute__((ext_vector_type(8))) short bf16x8;
typedef __attribute__((ext_vector_type(4))) float f32x4;

#define DEV __device__ __forceinline__

DEV float bf2f(u16 u) { union { u32 i; float f; } c; c.i = ((u32)u) << 16; return c.f; }
DEV u16 f2bf(float f) {  // round-to-nearest-even
  union { float f; u32 i; } c; c.f = f;
  u32 r = c.i + 0x7FFFu + ((c.i >> 16) & 1u);
  return (u16)(r >> 16);
}
DEV u32 pk2(float lo, float hi) { return (u32)f2bf(lo) | ((u32)f2bf(hi) << 16); }
DEV float rdsrc(const void* p, int e, int isb) {
  return isb ? bf2f(((const u16*)p)[e]) : ((const float*)p)[e];
}
DEV bf16x8 as_bf(uint4 v) { union { uint4 u; bf16x8 h; } c; c.u = v; return c.h; }

static constexpr int B = 2, N = 512, D = 128, F = 512;
static constexpr int NROW = B * N;  // 1024
static constexpr float EPS = 1e-5f;
static constexpr float NEG = -1e9f;
static constexpr float SCALE = 0.08838834764831845f;  // 1/sqrt(128)

// ---- fp32 small-weight region offsets ------------------------------------
#define OFF_PRE_W   0
#define OFF_PRE_B   256
#define OFF_PROJ_B  33152
#define OFF_BN_G    49664
#define OFF_BN_B    49792
#define OFF_BN_M    49920
#define OFF_BN_V    50048
#define OFF_OUT_B2  66560
#define OFF_PE      66688
#define OFF_BQ      132224
#define OFF_BK      181760
#define OFF_BV      231296
#define OFF_BO      280832
#define OFF_LN1G    281216
#define OFF_LN1B    281600
#define OFF_LN2G    281984
#define OFF_LN2B    282368
#define OFF_FB1     479360
#define OFF_FB2     677504
#define W_TOTAL     677888

// ---- packed-bf16 weight region (u32 units; [e8][col] uint4 of 8 K-elems) --
static constexpr int PB_PROJ = 0;
static constexpr int PB_OW1  = 8192;
static constexpr int PB_OW2  = 16384;
static constexpr int PB_L0   = 24576;
static constexpr int PB_LSTR = 98304;
static constexpr int PB_WO   = 24576;
static constexpr int PB_FW1  = 32768;
static constexpr int PB_FW2  = 65536;
static constexpr int PTOT    = 79872;   // total uint4 pack entries

struct NEnt { const void* s; int off, n; };
struct PEnt { const void* s1; const void* s2; int o1, o2, dst, lgn, cum; };
struct PrepArgs { NEnt nrm[19]; PEnt pk[21]; };

// ---------------------------------------------------------------------------
// MFMA helpers (round-8 verified): A rows 0..3 live, rows 4..15 zero, packed
// [e8][16] uint4 in LDS; B = [e8][ncol] uint4. D rows 0..3 -> lanes 0..15,
// regs 0..3. loadB/mmaR split the B-fragment load from the mma so loads can
// issue one phase early (the barrier's vmcnt(0) drain completes them under
// the preceding phase's compute).
// ---------------------------------------------------------------------------
template<int KT>
DEV f32x4 mmaKo(const uint4* __restrict__ aPk, const uint4* __restrict__ Bp,
                int ncol, int col, int lane, int kt0) {
  f32x4 acc = {0.f, 0.f, 0.f, 0.f};
  const int sub = lane >> 4;
  #pragma unroll
  for (int kt = 0; kt < KT; ++kt) {
    const int e8 = (kt0 + kt) * 4 + sub;
    acc = __builtin_amdgcn_mfma_f32_16x16x32_bf16(
        as_bf(aPk[e8 * 16 + (lane & 15)]),
        as_bf(Bp[(size_t)e8 * ncol + col]),
        acc, 0, 0, 0);
  }
  return acc;
}

template<int KT>
DEV void loadB(const uint4* __restrict__ Bp, int ncol, int col, int lane,
               int kt0, uint4* breg) {
  const int sub = lane >> 4;
  #pragma unroll
  for (int kt = 0; kt < KT; ++kt)
    breg[kt] = Bp[(size_t)((kt0 + kt) * 4 + sub) * ncol + col];
}

template<int KT>
DEV f32x4 mmaR(const uint4* __restrict__ aPk, const uint4* breg, int lane, int kt0) {
  f32x4 acc = {0.f, 0.f, 0.f, 0.f};
  const int sub = lane >> 4;
  #pragma unroll
  for (int kt = 0; kt < KT; ++kt) {
    const int e8 = (kt0 + kt) * 4 + sub;
    acc = __builtin_amdgcn_mfma_f32_16x16x32_bf16(
        as_bf(aPk[e8 * 16 + (lane & 15)]),
        as_bf(breg[kt]),
        acc, 0, 0, 0);
  }
  return acc;
}

// Epilogue pack, (r,d) decomposition
DEV void packRD(u32* aPkU, int r, int d, float v) {
  const float p = __shfl_xor(v, 1, 64);
  if (!(d & 1))
    aPkU[(((d >> 3) * 16 + r) << 2) + ((d >> 1) & 3)] = pk2(v, p);
}

// Epilogue pack, mma-epilogue decomposition (lanes 0..15 = cols, regs = rows)
DEV void packP16(u32* aPkU, int colbase, int lane, f32x4 v) {
  f32x4 p;
  #pragma unroll
  for (int g = 0; g < 4; ++g) p[g] = __shfl_xor(v[g], 1, 64);
  if (!(lane & 1)) {
    const int c = colbase + lane;
    const int e8 = c >> 3, slot = (c >> 1) & 3;
    #pragma unroll
    for (int g = 0; g < 4; ++g)
      aPkU[((e8 * 16 + g) << 2) + slot] = pk2(v[g], p[g]);
  }
}

// ---------------------------------------------------------------------------
// k_prep (512 blocks): 0..15 norm small tensors; 16..510 build packed
// weights; 511 normalizes mask. Each block self-detects dtype via bn_v.
// ---------------------------------------------------------------------------
__global__ __launch_bounds__(256) void k_prep(PrepArgs pa,
    const void* __restrict__ bnv, const void* __restrict__ maskp,
    int* __restrict__ flags, int* __restrict__ mbuf,
    float* __restrict__ W, u32* __restrict__ Wb)
{
  const int t = threadIdx.x, bid = blockIdx.x;
  __shared__ int s_nb, s_m4, s_m2;
  if (t == 0) { s_nb = 0; s_m4 = 0; s_m2 = 0; }
  __syncthreads();
  if (t < 64) {
    const u32 w = ((const u32*)bnv)[t];
    if (((w >> 8) & 0xFFu) != 0x3Fu || ((w >> 24) & 0xFFu) != 0x3Fu)
      atomicOr(&s_nb, 1);
  }
  __syncthreads();
  const int isb = s_nb ? 0 : 1;

  if (bid < 16) {
    for (int ten = 0; ten < 19; ++ten) {
      const NEnt E = pa.nrm[ten];
      for (int e = bid * 256 + t; e < E.n; e += 16 * 256)
        W[E.off + e] = rdsrc(E.s, e, isb);
    }
  } else if (bid < 511) {
    for (int g = (bid - 16) * 256 + t; g < PTOT; g += 495 * 256) {
      int ei = 0;
      #pragma unroll
      for (int k = 1; k < 21; ++k) if (g >= pa.pk[k].cum) ei = k;
      const PEnt E = pa.pk[ei];
      const int li = g - E.cum;
      const int e8 = li >> E.lgn, c = li & ((1 << E.lgn) - 1);
      float f[8];
      #pragma unroll
      for (int i = 0; i < 8; ++i) {
        const int si = ((e8 * 8 + i) << E.lgn) + c;
        f[i] = rdsrc(E.s1, E.o1 + si, isb);
        if (E.s2) f[i] += rdsrc(E.s2, E.o2 + si, isb);
      }
      uint4 w;
      w.x = pk2(f[0], f[1]); w.y = pk2(f[2], f[3]);
      w.z = pk2(f[4], f[5]); w.w = pk2(f[6], f[7]);
      ((uint4*)(Wb + E.dst))[li] = w;
    }
  } else {
    {
      const u32 w = ((const u32*)maskp)[t];
      if (!(w == 0u || w == 1u || w == 0x3F800000u)) atomicOr(&s_m4, 1);
      if (!(w == 0u || w == 1u || w == 0x10000u || w == 0x10001u ||
            w == 0x3F80u || w == 0x3F800000u || w == 0x3F803F80u)) atomicOr(&s_m2, 1);
    }
    __syncthreads();
    const int mode = (!s_m4) ? 4 : ((!s_m2) ? 2 : 1);
    if (t == 0) { flags[0] = isb; flags[1] = mode; }
    #pragma unroll
    for (int k = 0; k < 4; ++k) {
      const int e = k * 256 + t;
      int v;
      if (mode == 4)      v = (((const u32*)maskp)[e] != 0u);
      else if (mode == 2) v = (((const u16*)maskp)[e] != 0);
      else                v = (((const u8*)maskp)[e]  != 0);
      mbuf[e] = v;
    }
  }
}

// ---------------------------------------------------------------------------
// k_relq: collapsed pairwise chain + out-MLP + PE + QKV(layer 0).
// 4 rows/block, 256 blocks, 512 threads. Pack-in-epilogue; Q emitted packed
// (A-fragment layout, 1 KB/block); K packed with SCALE folded in.
// ---------------------------------------------------------------------------
__global__ __launch_bounds__(512) void k_relq(
    const void* __restrict__ relv, const float* __restrict__ W,
    const u32* __restrict__ Wb,
    const int* __restrict__ flags, const int* __restrict__ mbuf,
    const int* __restrict__ agent_id, float* __restrict__ xbuf,
    u32* __restrict__ qP, u32* __restrict__ kbT, u32* __restrict__ vbT)
{
  const int t = threadIdx.x;            // 0..511
  const int blk = blockIdx.x;
  const int row0 = blk * 4;
  const int b = row0 >> 9;
  const int wid = t >> 6;
  const int lane = t & 63;

  __shared__ uint4 aPk[2][256];         // K=128 GEMMs: e8 0..15
  __shared__ float wred[8][9];
  __shared__ float sT0[4], sT1[4], sMt;

  u32* a0 = (u32*)&aPk[0][0];
  u32* a1 = (u32*)&aPk[1][0];

  // --- P1: masked sums over j of rel channels; Mtot; zero aPk rows 4..15 ---
  float s0[4] = {0, 0, 0, 0}, s1[4] = {0, 0, 0, 0}, cnt;
  {
    const int j = t;
    const float m = (float)mbuf[b * N + j];
    cnt = m;
    if (flags[0]) {
      const u32* rel2 = (const u32*)relv;
      #pragma unroll
      for (int r = 0; r < 4; ++r) {
        const u32 u = rel2[(size_t)(row0 + r) * N + j];
        s0[r] += m * bf2f((u16)(u & 0xFFFFu));
        s1[r] += m * bf2f((u16)(u >> 16));
      }
    } else {
      const float2* relf = (const float2*)relv;
      #pragma unroll
      for (int r = 0; r < 4; ++r) {
        const float2 u = relf[(size_t)(row0 + r) * N + j];
        s0[r] += m * u.x; s1[r] += m * u.y;
      }
    }
  }
  if ((t & 15) >= 4) {                  // entries for rows 4..15 (never packed)
    const uint4 z = {0u, 0u, 0u, 0u};
    aPk[t >> 8][t & 255] = z;
  }
  #pragma unroll
  for (int o = 32; o > 0; o >>= 1) {
    #pragma unroll
    for (int r = 0; r < 4; ++r) {
      s0[r] += __shfl_xor(s0[r], o, 64);
      s1[r] += __shfl_xor(s1[r], o, 64);
    }
    cnt += __shfl_xor(cnt, o, 64);
  }
  if ((t & 63) == 0) {
    #pragma unroll
    for (int r = 0; r < 4; ++r) { wred[wid][r] = s0[r]; wred[wid][4 + r] = s1[r]; }
    wred[wid][8] = cnt;
  }
  __syncthreads();
  if (t < 4) {
    float a0v = 0, a1v = 0;
    #pragma unroll
    for (int w = 0; w < 8; ++w) { a0v += wred[w][t]; a1v += wred[w][4 + t]; }
    sT0[t] = a0v; sT1[t] = a1v;
  }
  if (t == 8) {
    float c = 0;
    #pragma unroll
    for (int w = 0; w < 8; ++w) c += wred[w][8];
    sMt = c;
  }
  __syncthreads();

  // --- P2: pooled -> pack a0 ---
  {
    const int r = t >> 7, c = t & 127;
    const int mi = mbuf[row0 + r];
    const float v = mi ? (sT0[r] * W[OFF_PRE_W + c] + sT1[r] * W[OFF_PRE_W + D + c]) / sMt
                         + W[OFF_PRE_B + c]
                       : 0.f;
    packRD(a0, r, c, v);
  }
  __syncthreads();

  // --- P3: pooled @ (P1+P2) -> z (mask, +bias) -> pack a1 ---
  {
    const int col = wid * 16 + (lane & 15);
    f32x4 acc = mmaKo<4>(&aPk[0][0], (const uint4*)(Wb + PB_PROJ), 128, col, lane, 0);
    if (lane < 16) {
      const float pb = W[OFF_PROJ_B + col];
      f32x4 v;
      #pragma unroll
      for (int g = 0; g < 4; ++g) v[g] = mbuf[row0 + g] ? acc[g] + pb : 0.f;
      packP16(a1, wid * 16, lane, v);
    }
  }
  __syncthreads();

  // --- P4: z @ out_w1 -> bn -> relu -> pack a0 ---
  {
    const int col = wid * 16 + (lane & 15);
    f32x4 acc = mmaKo<4>(&aPk[1][0], (const uint4*)(Wb + PB_OW1), 128, col, lane, 0);
    if (lane < 16) {
      const float bnm = W[OFF_BN_M + col];
      const float rs  = __frsqrt_rn(W[OFF_BN_V + col] + EPS);
      const float bg  = W[OFF_BN_G + col], bb = W[OFF_BN_B + col];
      f32x4 v;
      #pragma unroll
      for (int g = 0; g < 4; ++g) v[g] = fmaxf((acc[g] - bnm) * rs * bg + bb, 0.f);
      packP16(a0, wid * 16, lane, v);
    }
  }
  __syncthreads();

  // --- P5: relu_h @ out_w2 + out_b2 + pe -> xbuf + pack a1 ---
  {
    const int col = wid * 16 + (lane & 15);
    f32x4 acc = mmaKo<4>(&aPk[0][0], (const uint4*)(Wb + PB_OW2), 128, col, lane, 0);
    if (lane < 16) {
      const float ob = W[OFF_OUT_B2 + col];
      f32x4 v;
      #pragma unroll
      for (int g = 0; g < 4; ++g) {
        const int aid = agent_id[row0 + g];
        v[g] = acc[g] + ob + W[OFF_PE + aid * D + col];
        xbuf[(size_t)(row0 + g) * D + col] = v[g];
      }
      packP16(a1, wid * 16, lane, v);
    }
  }
  __syncthreads();

  // --- P6: QKV layer 0 (from a1) — Q packed (A-frag), K packed*SCALE, V packed ---
  {
    const int col = wid * 16 + (lane & 15);
    const int i0 = row0 & 511;
    #pragma unroll
    for (int m = 0; m < 3; ++m) {
      f32x4 acc = mmaKo<4>(&aPk[1][0], (const uint4*)(Wb + PB_L0 + m * 8192), 128, col, lane, 0);
      if (lane < 16) {
        const float bb = W[(m == 0 ? OFF_BQ : m == 1 ? OFF_BK : OFF_BV) + col];
        f32x4 v;
        #pragma unroll
        for (int g = 0; g < 4; ++g) v[g] = acc[g] + bb;
        if (m == 0) {
          f32x4 p;
          #pragma unroll
          for (int g = 0; g < 4; ++g) p[g] = __shfl_xor(v[g], 1, 64);
          if (!(lane & 1)) {
            const int e8 = col >> 3, slot = (col >> 1) & 3;
            #pragma unroll
            for (int g = 0; g < 4; ++g)
              qP[blk * 256 + (e8 * 4 + g) * 4 + slot] = pk2(v[g], p[g]);
          }
        } else if (m == 1) {
          f32x4 p;
          #pragma unroll
          for (int g = 0; g < 4; ++g) p[g] = __shfl_xor(v[g], 1, 64);
          if (!(lane & 1)) {
            const int e8 = col >> 3, slot = (col >> 1) & 3;
            #pragma unroll
            for (int g = 0; g < 4; ++g)
              ((u32*)kbT)[(((size_t)b * 16 + e8) * 512 + i0 + g) * 4 + slot]
                  = pk2(v[g] * SCALE, p[g] * SCALE);
          }
        } else {
          uint2 w;
          w.x = pk2(v[0], v[1]); w.y = pk2(v[2], v[3]);
          *(uint2*)(vbT + (((size_t)b * 64 + (i0 >> 3)) * 128 + col) * 4 + 2 * ((i0 >> 2) & 1)) = w;
        }
      }
    }
  }
}

// ---------------------------------------------------------------------------
// k_layer: fused attn + LN1 + FFN + LN2 [+ QKV(l+1)] for 4 rows/block.
// 256 blocks, 1024 threads. Pack-in-epilogue + one-phase-ahead B-operand
// prefetch into registers (barrier vmcnt(0) completes them under compute).
// Q flows packed (A-fragment layout) between layers; K carries SCALE.
// ---------------------------------------------------------------------------
__global__ __launch_bounds__(1024) void k_layer(
    const u32* __restrict__ qPin, const u32* __restrict__ kinT, const u32* __restrict__ vinT,
    const float* __restrict__ W, const u32* __restrict__ Wb, const int l, const int last,
    u32* __restrict__ qPout, u32* __restrict__ koutT, u32* __restrict__ voutT,
    const int* __restrict__ mbuf, float* __restrict__ xbuf, float* __restrict__ outp)
{
  const int t = threadIdx.x;            // 0..1023
  const int blk = blockIdx.x;
  const int row0 = blk * 4;
  const int b = row0 >> 9;
  const int wid = t >> 6;               // 0..15
  const int lane = t & 63;
  const int w8 = wid & 7, half = wid >> 3;

  const uint4* WOp = (const uint4*)(Wb + PB_L0 + l * PB_LSTR + PB_WO);
  const uint4* W1p = (const uint4*)(Wb + PB_L0 + l * PB_LSTR + PB_FW1);
  const uint4* W2p = (const uint4*)(Wb + PB_L0 + l * PB_LSTR + PB_FW2);
  const float* bo  = W + OFF_BO  + l * D;
  const float* g1  = W + OFF_LN1G + l * D;
  const float* b1  = W + OFF_LN1B + l * D;
  const float* fb1 = W + OFF_FB1 + l * F;
  const float* fb2 = W + OFF_FB2 + l * D;
  const float* g2  = W + OFF_LN2G + l * D;
  const float* b2v = W + OFF_LN2B + l * D;

  __shared__ float bufA[4][512];        // scores
  __shared__ float xs[4][D];
  __shared__ float pA[4][D], pB[4][D];  // K-split partials
  __shared__ uint4 aPk[2][1024];
  __shared__ float den[4];

  u32* a0 = (u32*)&aPk[0][0];
  u32* a1 = (u32*)&aPk[1][0];

  // Phase A: zero rows 4..15 of both aPk buffers; copy packed Q -> a0;
  // prefetch K fragments for phase B.
  for (int i = t; i < 2048; i += 1024)
    if ((i & 15) >= 4) {
      const uint4 z = {0u, 0u, 0u, 0u};
      aPk[i >> 10][i & 1023] = z;
    }
  if (t < 64)
    aPk[0][(t >> 2) * 16 + (t & 3)] = ((const uint4*)qPin)[blk * 64 + t];
  const uint4* Kp = (const uint4*)kinT + (size_t)b * 16 * 512;
  uint4 kB[2][4];
  #pragma unroll
  for (int ii = 0; ii < 2; ++ii)
    loadB<4>(Kp, 512, (wid + 16 * ii) * 16 + (lane & 15), lane, 0, kB[ii]);
  __syncthreads();

  // B: scores via MFMA (kB regs) — bias epilogue -> bufA; prefetch V.
  {
    #pragma unroll
    for (int ii = 0; ii < 2; ++ii) {
      const int col = (wid + 16 * ii) * 16 + (lane & 15);
      f32x4 acc = mmaR<4>(&aPk[0][0], kB[ii], lane, 0);
      if (lane < 16) {
        const float bias = mbuf[b * N + col] ? 0.f : NEG;
        #pragma unroll
        for (int g = 0; g < 4; ++g) bufA[g][col] = acc[g] + bias;
      }
    }
  }
  const uint4* Vp = (const uint4*)vinT + (size_t)b * 64 * 128;
  uint4 vB[8];
  loadB<8>(Vp, 128, w8 * 16 + (lane & 15), lane, half * 8, vB);
  __syncthreads();

  // C: softmax (wave r<4) — packs exp -> a1
  if (wid < 4) {
    const int r = wid;
    float pv[8];
    float mx = -1e30f;
    #pragma unroll
    for (int k = 0; k < 8; ++k) { pv[k] = bufA[r][lane + 64 * k]; mx = fmaxf(mx, pv[k]); }
    #pragma unroll
    for (int o = 32; o > 0; o >>= 1) mx = fmaxf(mx, __shfl_xor(mx, o, 64));
    float sum = 0.f;
    #pragma unroll
    for (int k = 0; k < 8; ++k) { pv[k] = __expf(pv[k] - mx); sum += pv[k]; }
    #pragma unroll
    for (int o = 32; o > 0; o >>= 1) sum += __shfl_xor(sum, o, 64);
    #pragma unroll
    for (int k = 0; k < 8; ++k) {
      const float pp = __shfl_xor(pv[k], 1, 64);
      if (!(lane & 1)) {
        const int c = lane + 64 * k;
        a1[(((c >> 3) * 16 + r) << 2) + ((c >> 1) & 3)] = pk2(pv[k], pp);
      }
    }
    if (lane == 0) den[r] = sum;
  }
  __syncthreads();

  // D: AV via MFMA (vB regs, K=512 split) -> partials; prefetch WO.
  {
    const int col = w8 * 16 + (lane & 15);
    f32x4 acc = mmaR<8>(&aPk[1][0], vB, lane, half * 8);
    if (lane < 16) {
      float* dst = half ? &pB[0][0] : &pA[0][0];
      #pragma unroll
      for (int g = 0; g < 4; ++g) dst[g * D + col] = acc[g];
    }
  }
  uint4 woB[2];
  loadB<2>(WOp, 128, w8 * 16 + (lane & 15), lane, half * 2, woB);
  __syncthreads();

  // D-combine: os = (pA+pB)/den -> pack a0
  if (t < 512) {
    const int r = t >> 7, d = t & 127;
    packRD(a0, r, d, (pA[r][d] + pB[r][d]) / den[r]);
  }
  __syncthreads();

  // E: WO via MFMA (woB regs, K=128 split) -> partials; prefetch W1.
  {
    const int col = w8 * 16 + (lane & 15);
    f32x4 acc = mmaR<2>(&aPk[0][0], woB, lane, half * 2);
    if (lane < 16) {
      float* dst = half ? &pB[0][0] : &pA[0][0];
      #pragma unroll
      for (int g = 0; g < 4; ++g) dst[g * D + col] = acc[g];
    }
  }
  uint4 w1B[2][4];
  #pragma unroll
  for (int ii = 0; ii < 2; ++ii)
    loadB<4>(W1p, 512, (wid + 16 * ii) * 16 + (lane & 15), lane, 0, w1B[ii]);
  __syncthreads();

  // F: residual + LN1 (wave r<4) — xs write + pack a1
  if (wid < 4) {
    const int r = wid;
    float tv[2];
    #pragma unroll
    for (int k = 0; k < 2; ++k) {
      const int d = lane + 64 * k;
      tv[k] = pA[r][d] + pB[r][d] + bo[d] + xbuf[(size_t)(row0 + r) * D + d];
    }
    float s = tv[0] + tv[1], sq = tv[0] * tv[0] + tv[1] * tv[1];
    #pragma unroll
    for (int o = 32; o > 0; o >>= 1) { s += __shfl_xor(s, o, 64); sq += __shfl_xor(sq, o, 64); }
    const float mean = s * (1.f / 128.f);
    const float var  = sq * (1.f / 128.f) - mean * mean;
    const float rstd = __frsqrt_rn(var + EPS);
    #pragma unroll
    for (int k = 0; k < 2; ++k) {
      const int d = lane + 64 * k;
      const float xn = (tv[k] - mean) * rstd * g1[d] + b1[d];
      xs[r][d] = xn;
      const float pp = __shfl_xor(xn, 1, 64);
      if (!(lane & 1))
        a1[(((d >> 3) * 16 + r) << 2) + ((d >> 1) & 3)] = pk2(xn, pp);
    }
  }
  __syncthreads();

  // G: FFN1 via MFMA (w1B regs) — relu epilogue packs -> a0; prefetch W2.
  {
    #pragma unroll
    for (int ii = 0; ii < 2; ++ii) {
      const int colbase = (wid + 16 * ii) * 16;
      f32x4 acc = mmaR<4>(&aPk[1][0], w1B[ii], lane, 0);
      if (lane < 16) {
        const float bb = fb1[colbase + lane];
        f32x4 v;
        #pragma unroll
        for (int g = 0; g < 4; ++g) v[g] = fmaxf(acc[g] + bb, 0.f);
        packP16(a0, colbase, lane, v);
      }
    }
  }
  uint4 w2B[8];
  loadB<8>(W2p, 128, w8 * 16 + (lane & 15), lane, half * 8, w2B);
  __syncthreads();

  // H: FFN2 via MFMA (w2B regs, K=512 split) -> partials; prefetch QKV(l+1).
  {
    const int col = w8 * 16 + (lane & 15);
    f32x4 acc = mmaR<8>(&aPk[0][0], w2B, lane, half * 8);
    if (lane < 16) {
      float* dst = half ? &pB[0][0] : &pA[0][0];
      #pragma unroll
      for (int g = 0; g < 4; ++g) dst[g * D + col] = acc[g];
    }
  }
  uint4 jB[2][4];
  if (!last) {
    #pragma unroll
    for (int it = 0; it < 2; ++it) {
      const int task = wid + 16 * it;
      if (task < 24) {
        const int m = task >> 3, c8 = task & 7;
        const uint4* Bp = (const uint4*)(Wb + PB_L0 + (l + 1) * PB_LSTR + m * 8192);
        loadB<4>(Bp, 128, c8 * 16 + (lane & 15), lane, 0, jB[it]);
      }
    }
  }
  __syncthreads();

  // I: residual + LN2 (wave r<4) — xbuf/outp write + pack a1 (if !last)
  if (wid < 4) {
    const int r = wid;
    float tv[2];
    #pragma unroll
    for (int k = 0; k < 2; ++k) {
      const int d = lane + 64 * k;
      tv[k] = pA[r][d] + pB[r][d] + fb2[d] + xs[r][d];
    }
    float s = tv[0] + tv[1], sq = tv[0] * tv[0] + tv[1] * tv[1];
    #pragma unroll
    for (int o = 32; o > 0; o >>= 1) { s += __shfl_xor(s, o, 64); sq += __shfl_xor(sq, o, 64); }
    const float mean = s * (1.f / 128.f);
    const float var  = sq * (1.f / 128.f) - mean * mean;
    const float rstd = __frsqrt_rn(var + EPS);
    #pragma unroll
    for (int k = 0; k < 2; ++k) {
      const int d = lane + 64 * k;
      const float xn = (tv[k] - mean) * rstd * g2[d] + b2v[d];
      xbuf[(size_t)(row0 + r) * D + d] = xn;
      if (last) outp[(size_t)(row0 + r) * D + d] = xn;
      const float pp = __shfl_xor(xn, 1, 64);
      if (!last && !(lane & 1))
        a1[(((d >> 3) * 16 + r) << 2) + ((d >> 1) & 3)] = pk2(xn, pp);
    }
  }

  // J: QKV for next layer (jB regs) — Q packed, K packed*SCALE, V packed.
  if (!last) {
    __syncthreads();
    const int i0 = row0 & 511;
    #pragma unroll
    for (int it = 0; it < 2; ++it) {
      const int task = wid + 16 * it;
      if (task < 24) {
        const int m = task >> 3, c8 = task & 7;
        const int col = c8 * 16 + (lane & 15);
        f32x4 acc = mmaR<4>(&aPk[1][0], jB[it], lane, 0);
        if (lane < 16) {
          const float bb = W[(m == 0 ? OFF_BQ : m == 1 ? OFF_BK : OFF_BV) + (l + 1) * D + col];
          f32x4 v;
          #pragma unroll
          for (int g = 0; g < 4; ++g) v[g] = acc[g] + bb;
          if (m == 0) {
            f32x4 p;
            #pragma unroll
            for (int g = 0; g < 4; ++g) p[g] = __shfl_xor(v[g], 1, 64);
            if (!(lane & 1)) {
              const int e8 = col >> 3, slot = (col >> 1) & 3;
              #pragma unroll
              for (int g = 0; g < 4; ++g)
                qPout[blk * 256 + (e8 * 4 + g) * 4 + slot] = pk2(v[g], p[g]);
            }
          } else if (m == 1) {
            f32x4 p;
            #pragma unroll
            for (int g = 0; g < 4; ++g) p[g] = __shfl_xor(v[g], 1, 64);
            if (!(lane & 1)) {
              const int e8 = col >> 3, slot = (col >> 1) & 3;
              #pragma unroll
              for (int g = 0; g < 4; ++g)
                ((u32*)koutT)[(((size_t)b * 16 + e8) * 512 + i0 + g) * 4 + slot]
                    = pk2(v[g] * SCALE, p[g] * SCALE);
            }
          } else {
            uint2 w;
            w.x = pk2(v[0], v[1]); w.y = pk2(v[2], v[3]);
            *(uint2*)(voutT + (((size_t)b * 64 + (i0 >> 3)) * 128 + col) * 4 + 2 * ((i0 >> 2) & 1)) = w;
          }
        }
      }
    }
  }
}

// ---------------------------------------------------------------------------
extern "C" void kernel_launch(void* const* d_in, const int* in_sizes, int n_in,
                              void* d_out, int out_size, void* d_ws, size_t ws_size,
                              hipStream_t stream) {
  // ws layout (4-byte units)
  int*   flags = (int*)d_ws;
  int*   mbuf  = flags + 16;
  float* xbuf  = (float*)d_ws + 1040;
  u32*   qP0   = (u32*)(xbuf + NROW * D);    // packed Q, [blk][e8][row] uint4
  u32*   qP1   = qP0 + 65536;
  u32*   kT0   = qP1 + 65536;                // [B][16][512] uint4 (pre-scaled)
  u32*   kT1   = kT0 + 65536;
  u32*   vT0   = kT1 + 65536;                // [B][64][128] uint4
  u32*   vT1   = vT0 + 65536;
  float* W     = (float*)(vT1 + 65536);
  u32*   Wb    = (u32*)(W + W_TOTAL);

  PrepArgs pa;
  {
    const NEnt nrm[19] = {
      {d_in[1],  OFF_PRE_W,  256}, {d_in[2],  OFF_PRE_B, 128},
      {d_in[4],  OFF_PROJ_B, 128},
      {d_in[6],  OFF_BN_G,   128}, {d_in[7],  OFF_BN_B,  128},
      {d_in[8],  OFF_BN_M,   128}, {d_in[9],  OFF_BN_V,  128},
      {d_in[11], OFF_OUT_B2, 128}, {d_in[12], OFF_PE,  16384},
      {d_in[14], OFF_BQ,     384}, {d_in[16], OFF_BK,    384},
      {d_in[18], OFF_BV,     384}, {d_in[20], OFF_BO,    384},
      {d_in[21], OFF_LN1G,   384}, {d_in[22], OFF_LN1B,  384},
      {d_in[23], OFF_LN2G,   384}, {d_in[24], OFF_LN2B,  384},
      {d_in[26], OFF_FB1,   1536}, {d_in[28], OFF_FB2,   384}};
    for (int i = 0; i < 19; ++i) pa.nrm[i] = nrm[i];

    pa.pk[0] = {d_in[3], d_in[3], 0, 16384, PB_PROJ, 7, 0};
    pa.pk[1] = {d_in[5],  nullptr, 0, 0, PB_OW1, 7, 2048};
    pa.pk[2] = {d_in[10], nullptr, 0, 0, PB_OW2, 7, 4096};
    for (int l = 0; l < 3; ++l) {
      const int lb = PB_L0 + l * PB_LSTR;
      const int cl = 6144 + l * 24576;
      pa.pk[3 + 6 * l + 0] = {d_in[13], nullptr, l * 16384, 0, lb,          7, cl};
      pa.pk[3 + 6 * l + 1] = {d_in[15], nullptr, l * 16384, 0, lb + 8192,   7, cl + 2048};
      pa.pk[3 + 6 * l + 2] = {d_in[17], nullptr, l * 16384, 0, lb + 16384,  7, cl + 4096};
      pa.pk[3 + 6 * l + 3] = {d_in[19], nullptr, l * 16384, 0, lb + PB_WO,  7, cl + 6144};
      pa.pk[3 + 6 * l + 4] = {d_in[25], nullptr, l * 65536, 0, lb + PB_FW1, 9, cl + 8192};
      pa.pk[3 + 6 * l + 5] = {d_in[27], nullptr, l * 65536, 0, lb + PB_FW2, 7, cl + 16384};
    }
  }
  const int* agent_id = (const int*)d_in[30];

  k_prep<<<512, 256, 0, stream>>>(pa, d_in[9], d_in[29], flags, mbuf, W, Wb);
  k_relq<<<NROW / 4, 512, 0, stream>>>(d_in[0], W, Wb, flags, mbuf, agent_id, xbuf,
                                       qP0, kT0, vT0);

  u32* qs_[2] = {qP0, qP1};
  u32* ks_[2] = {kT0, kT1};
  u32* vs_[2] = {vT0, vT1};
  for (int l = 0; l < 3; ++l) {
    const int cur = l & 1, nxt = cur ^ 1;
    const int last = (l == 2);
    k_layer<<<NROW / 4, 1024, 0, stream>>>(
        qs_[cur], ks_[cur], vs_[cur],
        W, Wb, l, last,
        qs_[nxt], ks_[nxt], vs_[nxt],
        mbuf, xbuf, last ? (float*)d_out : (float*)nullptr);
  }
}